// Round 6
// baseline (117.346 us; speedup 1.0000x reference)
//
#include <hip/hip_runtime.h>
#include <math.h>

#define NB 16
#define NN 64
#define NF 64
#define NH 4
#define NR 50
#define NC 256

typedef __attribute__((ext_vector_type(8))) short short8;
typedef __attribute__((ext_vector_type(4))) float f32x4;

// ---- wpack short offsets ----
#define WS_WE1R 0          // 512 entries
#define WS_WE2  4096       // 640 entries (512 We2 + 128 We2s)
#define WS_WX   9216       // 8192 entries, [q][w][nt][ks][lane]
#define WS_PO1  74752      // 2048
#define WS_NO1  91136      // 3072
#define WS_PO2  115712     // 512
#define WS_NO2  119808     // 512
#define WS_VE1  123904     // 512  -> shorts end 128000
// ---- float offsets ----
#define MID_F   64000
#define E1_F    (MID_F + 131072)
#define HAGG_F  (E1_F + 131072)
#define COMB_F  (HAGG_F + 262144)
#define ATT_F   (COMB_F + 786432)
#define XHAT_F  (ATT_F + 262144)
#define BS2_F   (XHAT_F + 262144)
// ---- h_e store: short offset ----
#define HE_S    ((BS2_F + 8) * 2)

__device__ __forceinline__ float siluf(float x) { return x / (1.f + __expf(-x)); }
__device__ __forceinline__ float tanhfast(float x) { return 1.f - 2.f / (__expf(2.f * x) + 1.f); }

__device__ __forceinline__ short f2bfs(float f) {
    __bf16 b = (__bf16)f;
    union { __bf16 b; short s; } u; u.b = b; return u.s;
}
__device__ __forceinline__ float bf1(ushort u) {
    union { unsigned u; float f; } c; c.u = ((unsigned)u) << 16; return c.f;
}
__device__ __forceinline__ float bflo(unsigned u) {
    union { unsigned u; float f; } c; c.u = u << 16; return c.f;
}
__device__ __forceinline__ float bfhi(unsigned u) {
    union { unsigned u; float f; } c; c.u = u & 0xFFFF0000u; return c.f;
}

__device__ __forceinline__ float wave_max(float v) {
#pragma unroll
    for (int s = 32; s >= 1; s >>= 1) v = fmaxf(v, __shfl_xor(v, s));
    return v;
}
__device__ __forceinline__ float wave_sum(float v) {
#pragma unroll
    for (int s = 32; s >= 1; s >>= 1) v += __shfl_xor(v, s);
    return v;
}

// =============== prep: weight packs + bsem2 + per-node precomputes ===============
__global__ __launch_bounds__(256)
void prep_kernel(const float* __restrict__ W_e1, const float* __restrict__ b_e1,
                 const float* __restrict__ W_e2, const float* __restrict__ b_e2,
                 const float* __restrict__ W_sem, const float* __restrict__ b_sem,
                 const float* __restrict__ W_xmix,
                 const float* __restrict__ W_post1, const float* __restrict__ W_node1,
                 const float* __restrict__ W_post2, const float* __restrict__ W_node2,
                 const float* __restrict__ W_vel1,
                 const float* __restrict__ h, const float* __restrict__ W_in,
                 const float* __restrict__ b_in,
                 short* __restrict__ wpack, float* __restrict__ mid_T,
                 float* __restrict__ e1, float* __restrict__ bs2)
{
    int blk = blockIdx.x, t = threadIdx.x;
    if (blk < 63) {
        int s = blk * 256 + t;
        if (s >= 16000) return;
        short8 val;
        if (s < 512) {               // W_e1 rbf part: K=64
            int cl = s & 15, g = (s >> 4) & 3, q = s >> 6;
            int ks = q & 1, nt = q >> 1;
            int c = nt * 16 + cl, k0 = 32 * ks + 8 * g;
#pragma unroll
            for (int i = 0; i < 8; i++) {
                int kr = k0 + i;
                float f = (kr < 50) ? W_e1[(128 + kr) * NF + c] : (kr == 50 ? W_e1[178 * NF + c] : 0.f);
                val[i] = f2bfs(f);
            }
            *(short8*)(&wpack[WS_WE1R + s * 8]) = val;
        } else if (s < 1152) {        // W_e2 (nt 0..3) + We2s = We2@Wsem (nt 4)
            int u = s - 512;
            int cl = u & 15, g = (u >> 4) & 3, q = u >> 6;
            int ks = q & 1, nt = q >> 1;
            int c = nt * 16 + cl, k0 = 32 * ks + 8 * g;
#pragma unroll
            for (int i = 0; i < 8; i++) {
                int k = k0 + i;
                float f;
                if (c < 64) f = W_e2[k * NF + c];
                else {
                    int cc = c - 64;
                    if (cc < 4) {
                        f = 0.f;
                        for (int m = 0; m < 64; m++) f += W_e2[k * NF + m] * W_sem[m * NH + cc];
                    } else f = 0.f;
                }
                val[i] = f2bfs(f);
            }
            *(short8*)(&wpack[WS_WE2 + u * 8]) = val;
        } else if (s < 9344) {        // W_xmix as V[f,(c,h)]: [q][w][nt][ks][lane]
            int u = s - 1152;
            int l = u & 63, ks = (u >> 6) & 1, nt = (u >> 7) & 3, w = (u >> 9) & 3, q = u >> 11;
            int lr = l & 15;
            int c = q * 64 + w * 16 + nt * 4 + (lr >> 2);
            int hh = lr & 3;
            int k0 = ks * 32 + (l >> 4) * 8;
#pragma unroll
            for (int i = 0; i < 8; i++) {
                int f = k0 + i;
                val[i] = f2bfs(W_xmix[(f * 4 + hh) * NC + c]);
            }
            *(short8*)(&wpack[WS_WX + u * 8]) = val;
        } else if (s < 11392) {       // W_post1 K=256 N=64
            int u = s - 9344;
            int cl = u & 15, g = (u >> 4) & 3, q = u >> 6;
            int ks = q & 7, nt = q >> 3;
            int c = nt * 16 + cl, k0 = 32 * ks + 8 * g;
#pragma unroll
            for (int i = 0; i < 8; i++) val[i] = f2bfs(W_post1[(k0 + i) * NF + c]);
            *(short8*)(&wpack[WS_PO1 + u * 8]) = val;
        } else if (s < 14464) {       // W_node1 K=384
            int u = s - 11392;
            int cl = u & 15, g = (u >> 4) & 3, q = u >> 6;
            int ks = q % 12, nt = q / 12;
            int c = nt * 16 + cl, k0 = 32 * ks + 8 * g;
#pragma unroll
            for (int i = 0; i < 8; i++) val[i] = f2bfs(W_node1[(k0 + i) * NF + c]);
            *(short8*)(&wpack[WS_NO1 + u * 8]) = val;
        } else if (s < 14976) {       // W_post2
            int u = s - 14464;
            int cl = u & 15, g = (u >> 4) & 3, q = u >> 6;
            int ks = q & 1, nt = q >> 1;
            int c = nt * 16 + cl, k0 = 32 * ks + 8 * g;
#pragma unroll
            for (int i = 0; i < 8; i++) val[i] = f2bfs(W_post2[(k0 + i) * NF + c]);
            *(short8*)(&wpack[WS_PO2 + u * 8]) = val;
        } else if (s < 15488) {       // W_node2
            int u = s - 14976;
            int cl = u & 15, g = (u >> 4) & 3, q = u >> 6;
            int ks = q & 1, nt = q >> 1;
            int c = nt * 16 + cl, k0 = 32 * ks + 8 * g;
#pragma unroll
            for (int i = 0; i < 8; i++) val[i] = f2bfs(W_node2[(k0 + i) * NF + c]);
            *(short8*)(&wpack[WS_NO2 + u * 8]) = val;
        } else {                      // W_vel1
            int u = s - 15488;
            int cl = u & 15, g = (u >> 4) & 3, q = u >> 6;
            int ks = q & 1, nt = q >> 1;
            int c = nt * 16 + cl, k0 = 32 * ks + 8 * g;
#pragma unroll
            for (int i = 0; i < 8; i++) val[i] = f2bfs(W_vel1[(k0 + i) * NF + c]);
            *(short8*)(&wpack[WS_VE1 + u * 8]) = val;
        }
    } else if (blk == 63) {
        if (t < 4) {
            float acc = b_sem[t];
            for (int m = 0; m < 64; m++) acc += b_e2[m] * W_sem[m * NH + t];
            bs2[t] = acc;
        }
    } else {
        int node = blk - 64;
        __shared__ float s_hn[64];
        if (t < 64) s_hn[t] = h[node * NF + t];
        __syncthreads();
        if (t < 64) {
            float acc = 0.f;
#pragma unroll 8
            for (int k = 0; k < 64; k++) acc += s_hn[k] * W_e1[k * NF + t];
            e1[node * 128 + t] = acc;
        } else if (t < 128) {
            int f = t - 64;
            float acc = b_e1[f];
#pragma unroll 8
            for (int k = 0; k < 64; k++) acc += s_hn[k] * W_e1[(64 + k) * NF + f];
            e1[node * 128 + 64 + f] = acc;
        } else if (t < 178) {
            int r = t - 128;
            float acc = 0.f;
#pragma unroll 8
            for (int k = 0; k < 64; k++) acc += s_hn[k] * W_in[k * NR + r];
            mid_T[r * 1024 + node] = acc;
        } else if (t >= 192 && t < 242) {
            int r = t - 192;
            float acc = b_in[r];
#pragma unroll 8
            for (int k = 0; k < 64; k++) acc += s_hn[k] * W_in[(64 + k) * NR + r];
            mid_T[(64 + r) * 1024 + node] = acc;
        }
    }
}

// =============== A: edge model through softmax + hagg; exports h_e/att/xhat ===============
__global__ __launch_bounds__(256)
void sake_edge_kernel(
    const float* __restrict__ x,
    const float* __restrict__ mid_T, const float* __restrict__ e1,
    const float* __restrict__ rbf_means, const float* __restrict__ rbf_betas,
    const float* __restrict__ b_e2, const float* __restrict__ bs2,
    const float* __restrict__ log_gamma,
    const short* __restrict__ wpack,
    float* __restrict__ hagg_g, float* __restrict__ att_g,
    float* __restrict__ xhat_g, short* __restrict__ heg)
{
    const int bi = blockIdx.x;
    const int b  = bi >> 6;
    const int i  = bi & 63;
    const int t  = threadIdx.x;
    const int w  = t >> 6, l = t & 63, lr = l & 15, lg = l >> 4;

    __shared__ __align__(16) short s_A[16 * 64 * 8];   // 16 KiB fragment-major
    __shared__ __align__(16) short s_he[64 * 72];      // 9 KiB
    __shared__ float s_xhat[256];
    __shared__ float s_att[256];
    __shared__ float s_sem[256];
    __shared__ float s_midi[52];

    const short8* A8  = (const short8*)s_A;
    short8*       A8w = (short8*)s_A;
    const short8* We1p = (const short8*)(wpack + WS_WE1R);
    const short8* We2p = (const short8*)(wpack + WS_WE2);

    // ---------- P0 ----------
    if (t < 50) s_midi[t] = mid_T[(64 + t) * 1024 + b * 64 + i];
    if (t < 64) {
        int j = t;
        float dx = x[(b * NN + j) * 3 + 0] - x[(b * NN + i) * 3 + 0];
        float dy = x[(b * NN + j) * 3 + 1] - x[(b * NN + i) * 3 + 1];
        float dz = x[(b * NN + j) * 3 + 2] - x[(b * NN + i) * 3 + 2];
        float d2 = dx * dx + dy * dy + dz * dz;
        float d  = sqrtf(fmaxf(d2, 0.f) + 1e-5f);
        float inv = 1.f / (d + 1e-5f);
        s_xhat[j * 4 + 0] = dx * inv;
        s_xhat[j * 4 + 1] = dy * inv;
        s_xhat[j * 4 + 2] = dz * inv;
        s_xhat[j * 4 + 3] = d;
    }
    __syncthreads();

    // ---------- P1: rbf A slots 0..7; export xhat ----------
    {
        xhat_g[bi * 256 + t] = s_xhat[t];
        int j = t & 63, p = t >> 6;
        float d = s_xhat[j * 4 + 3];
        float cut = 0.5f * (__cosf(d * 0.6283185307179586f) + 1.f) * (d < 5.f ? 1.f : 0.f);
        float emd = __expf(-d);
        const float* mcol = mid_T + b * 64 + j;
#pragma unroll
        for (int q = 0; q < 2; q++) {
            int sl = 2 * p + q;
            short8 val;
#pragma unroll
            for (int e = 0; e < 8; e++) {
                int r = sl * 8 + e;
                float o;
                if (r < 50) {
                    float m = mcol[r * 1024] + s_midi[r];
                    float df = emd - rbf_means[r];
                    o = cut * __expf(-rbf_betas[r] * df * df) * m;
                } else if (r == 50) o = d;
                else o = 0.f;
                val[e] = f2bfs(o);
            }
            A8w[sl * 64 + j] = val;
        }
    }
    __syncthreads();

    // ---------- P2 (MFMA K=64, C-init E1j+E1i): u -> slots 8..15 ----------
    {
        int f = w * 16 + lr;
        const float* e1b = e1 + (size_t)b * 64 * 128;
        float e1i_v = e1b[i * 128 + 64 + f];
        f32x4 acc[4];
#pragma unroll
        for (int jt = 0; jt < 4; jt++)
#pragma unroll
            for (int r = 0; r < 4; r++) {
                int j = jt * 16 + lg * 4 + r;
                acc[jt][r] = e1b[j * 128 + f] + e1i_v;
            }
#pragma unroll
        for (int ks = 0; ks < 2; ks++) {
            short8 bb = We1p[(w * 2 + ks) * 64 + l];
#pragma unroll
            for (int jt = 0; jt < 4; jt++) {
                short8 aa = A8[(ks * 4 + lg) * 64 + jt * 16 + lr];
                acc[jt] = __builtin_amdgcn_mfma_f32_16x16x32_bf16(aa, bb, acc[jt], 0, 0, 0);
            }
        }
#pragma unroll
        for (int jt = 0; jt < 4; jt++)
#pragma unroll
            for (int r = 0; r < 4; r++) {
                int j = jt * 16 + lg * 4 + r;
                s_A[(((f >> 3) + 8) * 64 + j) * 8 + (f & 7)] = f2bfs(siluf(acc[jt][r]));
            }
        __syncthreads();
    }

    // ---------- P3 (MFMA): h_e = u @ W_e2 + b_e2 -> s_he; wave0 also sem = u @ We2s ----------
    {
        f32x4 acc[4], acc2[4];
#pragma unroll
        for (int jt = 0; jt < 4; jt++) {
            acc[jt][0] = 0.f; acc[jt][1] = 0.f; acc[jt][2] = 0.f; acc[jt][3] = 0.f;
            acc2[jt][0] = 0.f; acc2[jt][1] = 0.f; acc2[jt][2] = 0.f; acc2[jt][3] = 0.f;
        }
#pragma unroll
        for (int ks = 0; ks < 2; ks++) {
            short8 bb = We2p[(w * 2 + ks) * 64 + l];
            short8 bb2 = We2p[(8 + ks) * 64 + l];
#pragma unroll
            for (int jt = 0; jt < 4; jt++) {
                short8 aa = A8[((8 + ks * 4 + lg)) * 64 + jt * 16 + lr];
                acc[jt] = __builtin_amdgcn_mfma_f32_16x16x32_bf16(aa, bb, acc[jt], 0, 0, 0);
                if (w == 0)
                    acc2[jt] = __builtin_amdgcn_mfma_f32_16x16x32_bf16(aa, bb2, acc2[jt], 0, 0, 0);
            }
        }
        float be2 = b_e2[w * 16 + lr];
        int f = w * 16 + lr;
#pragma unroll
        for (int jt = 0; jt < 4; jt++)
#pragma unroll
            for (int r = 0; r < 4; r++) {
                int j = jt * 16 + lg * 4 + r;
                s_he[j * 72 + f] = f2bfs(acc[jt][r] + be2);
            }
        if (w == 0 && lr < 4) {
#pragma unroll
            for (int jt = 0; jt < 4; jt++)
#pragma unroll
                for (int r = 0; r < 4; r++) {
                    int j = jt * 16 + lg * 4 + r;
                    s_sem[j * 4 + lr] = acc2[jt][r];
                }
        }
        __syncthreads();
    }

    // ---------- P3.5: export h_e fragments (A-pack order for kernel B) + P4 softmax ----------
    {
        short8* hegw = (short8*)heg;
#pragma unroll
        for (int p = 0; p < 2; p++) {
            int a = p * 256 + t;
            int jt = a >> 7, ks = (a >> 6) & 1, li = a & 63;
            int j = jt * 16 + (li & 15);
            int k0 = ks * 32 + ((li >> 4) & 3) * 8;
            hegw[(size_t)bi * 512 + a] = *(const short8*)(s_he + j * 72 + k0);
        }
    }
    {
        int hh = w, j = l;
        float acc = s_sem[j * 4 + hh] + bs2[hh];
        float cel = fmaxf(acc, 0.f) + fminf(0.f, 2.f * (__expf(0.5f * acc) - 1.f));
        float diag = (j == i) ? 1e5f : 0.f;
        float slog = cel - diag;
        float m1 = wave_max(slog);
        float e1v = __expf(slog - m1);
        float sem = e1v / wave_sum(e1v);
        float gam = __expf(log_gamma[hh]);
        float elog = -(s_xhat[j * 4 + 3] + diag) * gam;
        float m2 = wave_max(elog);
        float e2 = __expf(elog - m2);
        float euc = e2 / wave_sum(e2);
        float a = sem * euc;
        a = a / wave_sum(a);
        s_att[j * 4 + hh] = a;
    }
    __syncthreads();

    // ---------- P5: hagg -> global; export att ----------
    {
        att_g[bi * 256 + t] = s_att[t];
        int f2 = t >> 3, hh = (t >> 1) & 3, jh = t & 1;
        float a0 = 0.f, a1 = 0.f;
#pragma unroll 8
        for (int jj = 0; jj < 32; jj++) {
            int j = jh * 32 + jj;
            float at = s_att[j * 4 + hh];
            unsigned u = *(const unsigned*)(s_he + j * 72 + 2 * f2);
            a0 += bflo(u) * at;
            a1 += bfhi(u) * at;
        }
        a0 += __shfl_xor(a0, 1);
        a1 += __shfl_xor(a1, 1);
        if (!jh) {
            hagg_g[bi * 256 + (2 * f2) * 4 + hh]     = a0;
            hagg_g[bi * 256 + (2 * f2 + 1) * 4 + hh] = a1;
        }
    }
}

// =============== B: xmix GEMM, grid = (bi, quarter); G = h_e @ V, epilogue att/tanh/xhat ===============
__global__ __launch_bounds__(256)
void sake_xmix_kernel(
    const short* __restrict__ wpack, const float* __restrict__ att_g,
    const float* __restrict__ xhat_g, const short* __restrict__ heg,
    float* __restrict__ comb_g)
{
    const int blk = blockIdx.x;
    const int bi = blk >> 2, q = blk & 3;
    const int t = threadIdx.x;
    const int w = t >> 6, l = t & 63, lr = l & 15, lg = l >> 4;

    __shared__ __align__(16) short s_A[512 * 8];   // 8 KiB: h_e fragments
    __shared__ float s_att[256];
    __shared__ float s_xh[256];

    const short8* A8 = (const short8*)s_A;
    short8* A8w = (short8*)s_A;
    const short8* hep = (const short8*)(heg) + (size_t)bi * 512;
    const short8* Wxp = (const short8*)(wpack + WS_WX);

    A8w[t] = hep[t];
    A8w[256 + t] = hep[256 + t];
    s_att[t] = att_g[bi * 256 + t];
    s_xh[t] = xhat_g[bi * 256 + t];
    __syncthreads();

    f32x4 acc[4][4];
#pragma unroll
    for (int jt = 0; jt < 4; jt++)
#pragma unroll
        for (int nt = 0; nt < 4; nt++) { acc[jt][nt][0] = 0.f; acc[jt][nt][1] = 0.f; acc[jt][nt][2] = 0.f; acc[jt][nt][3] = 0.f; }

#pragma unroll
    for (int ks = 0; ks < 2; ks++) {
        short8 aa[4];
#pragma unroll
        for (int jt = 0; jt < 4; jt++) aa[jt] = A8[(jt * 2 + ks) * 64 + l];
#pragma unroll
        for (int nt = 0; nt < 4; nt++) {
            short8 bb = Wxp[((((q * 4 + w) * 4 + nt) * 2) + ks) * 64 + l];
#pragma unroll
            for (int jt = 0; jt < 4; jt++)
                acc[jt][nt] = __builtin_amdgcn_mfma_f32_16x16x32_bf16(aa[jt], bb, acc[jt][nt], 0, 0, 0);
        }
    }

    // epilogue: coeff = tanh(sum_h att*G); comb = mean_j xhat*coeff
    float p[4][3];
#pragma unroll
    for (int nt = 0; nt < 4; nt++) { p[nt][0] = 0.f; p[nt][1] = 0.f; p[nt][2] = 0.f; }
    int hh = lr & 3;
#pragma unroll
    for (int jt = 0; jt < 4; jt++)
#pragma unroll
        for (int r = 0; r < 4; r++) {
            int j = jt * 16 + lg * 4 + r;
            float ax = s_xh[j * 4 + 0], ay = s_xh[j * 4 + 1], az = s_xh[j * 4 + 2];
            float at = s_att[j * 4 + hh];
#pragma unroll
            for (int nt = 0; nt < 4; nt++) {
                float s = at * acc[jt][nt][r];
                s += __shfl_xor(s, 1);
                s += __shfl_xor(s, 2);
                float th = tanhfast(s);
                p[nt][0] += ax * th; p[nt][1] += ay * th; p[nt][2] += az * th;
            }
        }
#pragma unroll
    for (int nt = 0; nt < 4; nt++) {
#pragma unroll
        for (int k3 = 0; k3 < 3; k3++) {
            float val = p[nt][k3];
            val += __shfl_xor(val, 16);
            val += __shfl_xor(val, 32);
            if (lg == 0 && (l & 3) == 0) {
                int c = q * 64 + w * 16 + nt * 4 + (lr >> 2);
                comb_g[bi * 768 + c * 3 + k3] = val * (1.f / 64.f);
            }
        }
    }
}

// =============== tail: 64 blocks x 16-node tiles, MFMA MLP chain ===============
__global__ __launch_bounds__(256)
void sake_tail_kernel(
    const float* __restrict__ h, const float* __restrict__ x, const float* __restrict__ v,
    const float* __restrict__ hagg_g, const float* __restrict__ comb_g,
    const float* __restrict__ b_post1, const float* __restrict__ b_post2,
    const float* __restrict__ b_node1, const float* __restrict__ b_node2,
    const float* __restrict__ b_vel1,
    const float* __restrict__ W_vel2, const float* __restrict__ W_vmix,
    const short* __restrict__ wpack,
    float* __restrict__ out_h, float* __restrict__ out_x, float* __restrict__ out_v)
{
    const int g0 = blockIdx.x * 16;
    const int t = threadIdx.x;
    const int w = t >> 6, l = t & 63, lr = l & 15, lg = l >> 4;

    __shared__ __align__(16) short s_Aa[88 * 16 * 8];
    __shared__ float s_wv[256];
    __shared__ float s_wv2[64];
    __shared__ float s_red[4][16];

    const short8* A8  = (const short8*)s_Aa;
    const short8* PO1p = (const short8*)(wpack + WS_PO1);
    const short8* NO1p = (const short8*)(wpack + WS_NO1);
    const short8* PO2p = (const short8*)(wpack + WS_PO2);
    const short8* NO2p = (const short8*)(wpack + WS_NO2);
    const short8* VE1p = (const short8*)(wpack + WS_VE1);

    {
        s_wv[t] = W_vmix[t];
        if (t < 64) s_wv2[t] = W_vel2[t];
        int n = t & 15, c0 = (t >> 4) * 16;
        const float* cg = comb_g + (g0 + n) * 768;
        const float* ha = hagg_g + (g0 + n) * 256;
#pragma unroll
        for (int cc = 0; cc < 16; cc++) {
            int c = c0 + cc;
            float v0 = cg[c * 3 + 0], v1 = cg[c * 3 + 1], v2 = cg[c * 3 + 2];
            float hcp = v0 * v0 + v1 * v1 + v2 * v2;
            s_Aa[((c >> 3) * 16 + n) * 8 + (c & 7)] = f2bfs(hcp);
            s_Aa[((40 + (c >> 3)) * 16 + n) * 8 + (c & 7)] = f2bfs(ha[c]);
        }
        int f0 = (t >> 4) * 4;
#pragma unroll
        for (int ff = 0; ff < 4; ff++) {
            int f = f0 + ff;
            s_Aa[((32 + (f >> 3)) * 16 + n) * 8 + (f & 7)] = f2bfs(h[(g0 + n) * 64 + f]);
        }
    }
    __syncthreads();

    {   // post1 (K=256) -> slots 80..87
        f32x4 acc = {0.f, 0.f, 0.f, 0.f};
#pragma unroll
        for (int ks = 0; ks < 8; ks++) {
            short8 aa = A8[(ks * 4 + lg) * 16 + lr];
            short8 bb = PO1p[((w * 8 + ks) * 4 + lg) * 16 + lr];
            acc = __builtin_amdgcn_mfma_f32_16x16x32_bf16(aa, bb, acc, 0, 0, 0);
        }
        int f = w * 16 + lr;
        float bp = b_post1[f];
        __syncthreads();
#pragma unroll
        for (int r = 0; r < 4; r++) {
            int n = lg * 4 + r;
            s_Aa[((80 + (f >> 3)) * 16 + n) * 8 + (f & 7)] = f2bfs(siluf(acc[r] + bp));
        }
        __syncthreads();
    }
    {   // post2 -> hcomb slots 72..79
        f32x4 acc = {0.f, 0.f, 0.f, 0.f};
#pragma unroll
        for (int ks = 0; ks < 2; ks++) {
            short8 aa = A8[((80 + ks * 4 + lg)) * 16 + lr];
            short8 bb = PO2p[((w * 2 + ks) * 4 + lg) * 16 + lr];
            acc = __builtin_amdgcn_mfma_f32_16x16x32_bf16(aa, bb, acc, 0, 0, 0);
        }
        int f = w * 16 + lr;
        float bp = b_post2[f];
#pragma unroll
        for (int r = 0; r < 4; r++) {
            int n = lg * 4 + r;
            s_Aa[((72 + (f >> 3)) * 16 + n) * 8 + (f & 7)] = f2bfs(siluf(acc[r] + bp));
        }
        __syncthreads();
    }
    {   // node1 (K=384) -> slots 0..7
        f32x4 acc = {0.f, 0.f, 0.f, 0.f};
#pragma unroll
        for (int ks = 0; ks < 12; ks++) {
            short8 aa = A8[((32 + ks * 4 + lg)) * 16 + lr];
            short8 bb = NO1p[((w * 12 + ks) * 4 + lg) * 16 + lr];
            acc = __builtin_amdgcn_mfma_f32_16x16x32_bf16(aa, bb, acc, 0, 0, 0);
        }
        int f = w * 16 + lr;
        float bp = b_node1[f];
#pragma unroll
        for (int r = 0; r < 4; r++) {
            int n = lg * 4 + r;
            s_Aa[((f >> 3) * 16 + n) * 8 + (f & 7)] = f2bfs(siluf(acc[r] + bp));
        }
        __syncthreads();
    }
    {   // node2 + residual -> out_h, vel1-A slots 8..15
        f32x4 acc = {0.f, 0.f, 0.f, 0.f};
#pragma unroll
        for (int ks = 0; ks < 2; ks++) {
            short8 aa = A8[(ks * 4 + lg) * 16 + lr];
            short8 bb = NO2p[((w * 2 + ks) * 4 + lg) * 16 + lr];
            acc = __builtin_amdgcn_mfma_f32_16x16x32_bf16(aa, bb, acc, 0, 0, 0);
        }
        int f = w * 16 + lr;
        float bp = b_node2[f];
#pragma unroll
        for (int r = 0; r < 4; r++) {
            int n = lg * 4 + r;
            float ho = h[(g0 + n) * 64 + f] + siluf(acc[r] + bp);
            out_h[(g0 + n) * 64 + f] = ho;
            s_Aa[((8 + (f >> 3)) * 16 + n) * 8 + (f & 7)] = f2bfs(ho);
        }
        __syncthreads();
    }
    {   // vel1 -> gate partials
        f32x4 acc = {0.f, 0.f, 0.f, 0.f};
#pragma unroll
        for (int ks = 0; ks < 2; ks++) {
            short8 aa = A8[((8 + ks * 4 + lg)) * 16 + lr];
            short8 bb = VE1p[((w * 2 + ks) * 4 + lg) * 16 + lr];
            acc = __builtin_amdgcn_mfma_f32_16x16x32_bf16(aa, bb, acc, 0, 0, 0);
        }
        int f = w * 16 + lr;
        float bp = b_vel1[f];
        float wv2 = s_wv2[f];
#pragma unroll
        for (int r = 0; r < 4; r++) {
            float pv = siluf(acc[r] + bp) * wv2;
            pv += __shfl_xor(pv, 1); pv += __shfl_xor(pv, 2);
            pv += __shfl_xor(pv, 4); pv += __shfl_xor(pv, 8);
            if (lr == 0) s_red[w][lg * 4 + r] = pv;
        }
        __syncthreads();
    }
    {   // gate + delta_v + outputs
        int n = t >> 4, qq = t & 15;
        float p0 = 0.f, p1 = 0.f, p2 = 0.f;
        const float* cg = comb_g + (g0 + n) * 768;
#pragma unroll
        for (int cc = 0; cc < 16; cc++) {
            int c = qq * 16 + cc;
            float wv = s_wv[c];
            p0 += cg[c * 3 + 0] * wv;
            p1 += cg[c * 3 + 1] * wv;
            p2 += cg[c * 3 + 2] * wv;
        }
        p0 += __shfl_xor(p0, 1); p0 += __shfl_xor(p0, 2); p0 += __shfl_xor(p0, 4); p0 += __shfl_xor(p0, 8);
        p1 += __shfl_xor(p1, 1); p1 += __shfl_xor(p1, 2); p1 += __shfl_xor(p1, 4); p1 += __shfl_xor(p1, 8);
        p2 += __shfl_xor(p2, 1); p2 += __shfl_xor(p2, 2); p2 += __shfl_xor(p2, 4); p2 += __shfl_xor(p2, 8);
        if (qq == 0) {
            float g = s_red[0][n] + s_red[1][n] + s_red[2][n] + s_red[3][n];
            g = 2.f / (1.f + __expf(-g));
            float dv0 = p0 + g * v[(g0 + n) * 3 + 0];
            float dv1 = p1 + g * v[(g0 + n) * 3 + 1];
            float dv2 = p2 + g * v[(g0 + n) * 3 + 2];
            out_v[(g0 + n) * 3 + 0] = dv0;
            out_v[(g0 + n) * 3 + 1] = dv1;
            out_v[(g0 + n) * 3 + 2] = dv2;
            out_x[(g0 + n) * 3 + 0] = x[(g0 + n) * 3 + 0] + dv0;
            out_x[(g0 + n) * 3 + 1] = x[(g0 + n) * 3 + 1] + dv1;
            out_x[(g0 + n) * 3 + 2] = x[(g0 + n) * 3 + 2] + dv2;
        }
    }
}

extern "C" void kernel_launch(void* const* d_in, const int* in_sizes, int n_in,
                              void* d_out, int out_size, void* d_ws, size_t ws_size,
                              hipStream_t stream) {
    const float* h        = (const float*)d_in[0];
    const float* x        = (const float*)d_in[1];
    const float* v        = (const float*)d_in[2];
    const float* W_in     = (const float*)d_in[3];
    const float* b_in     = (const float*)d_in[4];
    const float* rbf_m    = (const float*)d_in[5];
    const float* rbf_b    = (const float*)d_in[6];
    const float* W_e1     = (const float*)d_in[7];
    const float* b_e1     = (const float*)d_in[8];
    const float* W_e2     = (const float*)d_in[9];
    const float* b_e2     = (const float*)d_in[10];
    const float* W_sem    = (const float*)d_in[11];
    const float* b_sem    = (const float*)d_in[12];
    const float* log_g    = (const float*)d_in[13];
    const float* W_xmix   = (const float*)d_in[14];
    const float* W_post1  = (const float*)d_in[15];
    const float* b_post1  = (const float*)d_in[16];
    const float* W_post2  = (const float*)d_in[17];
    const float* b_post2  = (const float*)d_in[18];
    const float* W_node1  = (const float*)d_in[19];
    const float* b_node1  = (const float*)d_in[20];
    const float* W_node2  = (const float*)d_in[21];
    const float* b_node2  = (const float*)d_in[22];
    const float* W_vel1   = (const float*)d_in[23];
    const float* b_vel1   = (const float*)d_in[24];
    const float* W_vel2   = (const float*)d_in[25];
    const float* W_vmix   = (const float*)d_in[26];

    float* out   = (float*)d_out;
    float* out_h = out;
    float* out_x = out + NB * NN * NF;
    float* out_v = out + NB * NN * NF + NB * NN * 3;

    short* wpack = (short*)d_ws;
    float* wsf   = (float*)d_ws;
    float* mid_T = wsf + MID_F;
    float* e1    = wsf + E1_F;
    float* hagg  = wsf + HAGG_F;
    float* comb  = wsf + COMB_F;
    float* att   = wsf + ATT_F;
    float* xhat  = wsf + XHAT_F;
    float* bs2   = wsf + BS2_F;
    short* heg   = wpack + HE_S;

    prep_kernel<<<64 + 1024, 256, 0, stream>>>(
        W_e1, b_e1, W_e2, b_e2, W_sem, b_sem, W_xmix,
        W_post1, W_node1, W_post2, W_node2, W_vel1,
        h, W_in, b_in, wpack, mid_T, e1, bs2);

    sake_edge_kernel<<<NB * NN, 256, 0, stream>>>(
        x, mid_T, e1, rbf_m, rbf_b, b_e2, bs2, log_g,
        wpack, hagg, att, xhat, heg);

    sake_xmix_kernel<<<NB * NN * 4, 256, 0, stream>>>(
        wpack, att, xhat, heg, comb);

    sake_tail_kernel<<<64, 256, 0, stream>>>(
        h, x, v, hagg, comb,
        b_post1, b_post2, b_node1, b_node2, b_vel1,
        W_vel2, W_vmix, wpack, out_h, out_x, out_v);
}

// Round 7
// 61.863 us; speedup vs baseline: 1.8969x; 1.8969x over previous
//
#include <hip/hip_runtime.h>
#include <math.h>

#define NB 16
#define NN 64
#define NF 64
#define NH 4
#define NR 50
#define NC 256

typedef __attribute__((ext_vector_type(8))) short short8;
typedef __attribute__((ext_vector_type(4))) float f32x4;

// ---- wpack short offsets ----
#define WS_WE1R 0          // 512 entries (K=64 rbf part of W_e1)
#define WS_WE2  4096       // 640 entries (512 We2 + 128 We2s)
#define WS_WX   9216       // 8192 entries [wn(16)][ks8(8)][lane]
#define WS_PO1  74752      // 2048
#define WS_NO1  91136      // 3072
#define WS_PO2  115712     // 512
#define WS_NO2  119808     // 512
#define WS_VE1  123904     // 512 -> shorts end 128000
// ---- float offsets ----
#define MID_F   64000
#define E1_F    (MID_F + 131072)
#define HAGG_F  (E1_F + 131072)
#define COMB_F  (HAGG_F + 262144)
#define BS2_F   (COMB_F + 786432)

__device__ __forceinline__ float siluf(float x) { return x / (1.f + __expf(-x)); }
__device__ __forceinline__ float tanhfast(float x) { return 1.f - 2.f / (__expf(2.f * x) + 1.f); }

__device__ __forceinline__ short f2bfs(float f) {
    __bf16 b = (__bf16)f;
    union { __bf16 b; short s; } u; u.b = b; return u.s;
}
__device__ __forceinline__ float bf1(ushort u) {
    union { unsigned u; float f; } c; c.u = ((unsigned)u) << 16; return c.f;
}
__device__ __forceinline__ float bflo(unsigned u) {
    union { unsigned u; float f; } c; c.u = u << 16; return c.f;
}
__device__ __forceinline__ float bfhi(unsigned u) {
    union { unsigned u; float f; } c; c.u = u & 0xFFFF0000u; return c.f;
}

__device__ __forceinline__ float wave_max(float v) {
#pragma unroll
    for (int s = 32; s >= 1; s >>= 1) v = fmaxf(v, __shfl_xor(v, s));
    return v;
}
__device__ __forceinline__ float wave_sum(float v) {
#pragma unroll
    for (int s = 32; s >= 1; s >>= 1) v += __shfl_xor(v, s);
    return v;
}

// =============== prep: weight packs + bs2 + per-node precomputes ===============
__global__ __launch_bounds__(256)
void prep_kernel(const float* __restrict__ W_e1, const float* __restrict__ b_e1,
                 const float* __restrict__ W_e2, const float* __restrict__ b_e2,
                 const float* __restrict__ W_sem, const float* __restrict__ b_sem,
                 const float* __restrict__ W_xmix,
                 const float* __restrict__ W_post1, const float* __restrict__ W_node1,
                 const float* __restrict__ W_post2, const float* __restrict__ W_node2,
                 const float* __restrict__ W_vel1,
                 const float* __restrict__ h, const float* __restrict__ W_in,
                 const float* __restrict__ b_in,
                 short* __restrict__ wpack, float* __restrict__ mid_T,
                 float* __restrict__ e1, float* __restrict__ bs2)
{
    int blk = blockIdx.x, t = threadIdx.x;
    if (blk < 63) {
        int s = blk * 256 + t;
        if (s >= 16000) return;
        short8 val;
        if (s < 512) {               // W_e1 rbf part K=64
            int cl = s & 15, g = (s >> 4) & 3, q = s >> 6;
            int ks = q & 1, nt = q >> 1;
            int c = nt * 16 + cl, k0 = 32 * ks + 8 * g;
#pragma unroll
            for (int i = 0; i < 8; i++) {
                int kr = k0 + i;
                float f = (kr < 50) ? W_e1[(128 + kr) * NF + c] : (kr == 50 ? W_e1[178 * NF + c] : 0.f);
                val[i] = f2bfs(f);
            }
            *(short8*)(&wpack[WS_WE1R + s * 8]) = val;
        } else if (s < 1152) {        // W_e2 (nt 0..3) + We2s = We2@Wsem (nt 4)
            int u = s - 512;
            int cl = u & 15, g = (u >> 4) & 3, q = u >> 6;
            int ks = q & 1, nt = q >> 1;
            int c = nt * 16 + cl, k0 = 32 * ks + 8 * g;
#pragma unroll
            for (int i = 0; i < 8; i++) {
                int k = k0 + i;
                float f;
                if (c < 64) f = W_e2[k * NF + c];
                else {
                    int cc = c - 64;
                    if (cc < 4) {
                        f = 0.f;
                        for (int m = 0; m < 64; m++) f += W_e2[k * NF + m] * W_sem[m * NH + cc];
                    } else f = 0.f;
                }
                val[i] = f2bfs(f);
            }
            *(short8*)(&wpack[WS_WE2 + u * 8]) = val;
        } else if (s < 9344) {        // W_xmix K=256 N=256, round-4 order
            int u = s - 1152;
            int cl = u & 15, g = (u >> 4) & 3, q = u >> 6;
            int ks = q & 7, wn = q >> 3;
            int c = (wn >> 2) * 64 + (wn & 3) * 16 + cl, k0 = 32 * ks + 8 * g;
#pragma unroll
            for (int i = 0; i < 8; i++) val[i] = f2bfs(W_xmix[(k0 + i) * NC + c]);
            *(short8*)(&wpack[WS_WX + u * 8]) = val;
        } else if (s < 11392) {       // W_post1 K=256 N=64
            int u = s - 9344;
            int cl = u & 15, g = (u >> 4) & 3, q = u >> 6;
            int ks = q & 7, nt = q >> 3;
            int c = nt * 16 + cl, k0 = 32 * ks + 8 * g;
#pragma unroll
            for (int i = 0; i < 8; i++) val[i] = f2bfs(W_post1[(k0 + i) * NF + c]);
            *(short8*)(&wpack[WS_PO1 + u * 8]) = val;
        } else if (s < 14464) {       // W_node1 K=384
            int u = s - 11392;
            int cl = u & 15, g = (u >> 4) & 3, q = u >> 6;
            int ks = q % 12, nt = q / 12;
            int c = nt * 16 + cl, k0 = 32 * ks + 8 * g;
#pragma unroll
            for (int i = 0; i < 8; i++) val[i] = f2bfs(W_node1[(k0 + i) * NF + c]);
            *(short8*)(&wpack[WS_NO1 + u * 8]) = val;
        } else if (s < 14976) {       // W_post2
            int u = s - 14464;
            int cl = u & 15, g = (u >> 4) & 3, q = u >> 6;
            int ks = q & 1, nt = q >> 1;
            int c = nt * 16 + cl, k0 = 32 * ks + 8 * g;
#pragma unroll
            for (int i = 0; i < 8; i++) val[i] = f2bfs(W_post2[(k0 + i) * NF + c]);
            *(short8*)(&wpack[WS_PO2 + u * 8]) = val;
        } else if (s < 15488) {       // W_node2
            int u = s - 14976;
            int cl = u & 15, g = (u >> 4) & 3, q = u >> 6;
            int ks = q & 1, nt = q >> 1;
            int c = nt * 16 + cl, k0 = 32 * ks + 8 * g;
#pragma unroll
            for (int i = 0; i < 8; i++) val[i] = f2bfs(W_node2[(k0 + i) * NF + c]);
            *(short8*)(&wpack[WS_NO2 + u * 8]) = val;
        } else {                      // W_vel1
            int u = s - 15488;
            int cl = u & 15, g = (u >> 4) & 3, q = u >> 6;
            int ks = q & 1, nt = q >> 1;
            int c = nt * 16 + cl, k0 = 32 * ks + 8 * g;
#pragma unroll
            for (int i = 0; i < 8; i++) val[i] = f2bfs(W_vel1[(k0 + i) * NF + c]);
            *(short8*)(&wpack[WS_VE1 + u * 8]) = val;
        }
    } else if (blk == 63) {
        if (t < 4) {
            float acc = b_sem[t];
            for (int m = 0; m < 64; m++) acc += b_e2[m] * W_sem[m * NH + t];
            bs2[t] = acc;
        }
    } else {
        int node = blk - 64;
        __shared__ float s_hn[64];
        if (t < 64) s_hn[t] = h[node * NF + t];
        __syncthreads();
        if (t < 64) {
            float acc = 0.f;
#pragma unroll 8
            for (int k = 0; k < 64; k++) acc += s_hn[k] * W_e1[k * NF + t];
            e1[node * 128 + t] = acc;
        } else if (t < 128) {
            int f = t - 64;
            float acc = b_e1[f];
#pragma unroll 8
            for (int k = 0; k < 64; k++) acc += s_hn[k] * W_e1[(64 + k) * NF + f];
            e1[node * 128 + 64 + f] = acc;
        } else if (t < 178) {
            int r = t - 128;
            float acc = 0.f;
#pragma unroll 8
            for (int k = 0; k < 64; k++) acc += s_hn[k] * W_in[k * NR + r];
            mid_T[r * 1024 + node] = acc;
        } else if (t >= 192 && t < 242) {
            int r = t - 192;
            float acc = b_in[r];
#pragma unroll 8
            for (int k = 0; k < 64; k++) acc += s_hn[k] * W_in[(64 + k) * NR + r];
            mid_T[(64 + r) * 1024 + node] = acc;
        }
    }
}

// =============== edge: one block per (b,i); 512 threads = 8 waves ===============
__global__ __launch_bounds__(512)
void sake_edge_kernel(
    const float* __restrict__ x,
    const float* __restrict__ mid_T, const float* __restrict__ e1,
    const float* __restrict__ rbf_means, const float* __restrict__ rbf_betas,
    const float* __restrict__ b_e2, const float* __restrict__ bs2,
    const float* __restrict__ log_gamma,
    const short* __restrict__ wpack,
    float* __restrict__ hagg_g, float* __restrict__ comb_g)
{
    const int bi = blockIdx.x;
    const int b  = bi >> 6;
    const int i  = bi & 63;
    const int t  = threadIdx.x;
    const int w  = t >> 6, l = t & 63, lr = l & 15, lg = l >> 4;
    const int wn = w >> 1, wj = w & 1;   // wn: N/f-tile (0..3); wj: jt-half (0..1)

    __shared__ __align__(16) short s_A[16 * 64 * 8];   // 16 KiB fragment-major A; reused as f32 partials
    __shared__ __align__(16) short s_he[64 * 72];      // 9 KiB h_e bf16
    __shared__ float s_xhat[256];
    __shared__ float s_att[256];
    __shared__ float s_sem[256];
    __shared__ float s_midi[52];

    const short8* A8  = (const short8*)s_A;
    short8*       A8w = (short8*)s_A;
    const short8* We1p = (const short8*)(wpack + WS_WE1R);
    const short8* We2p = (const short8*)(wpack + WS_WE2);
    const short8* Wxp  = (const short8*)(wpack + WS_WX);

    // ---------- P0 ----------
    if (t < 50) s_midi[t] = mid_T[(64 + t) * 1024 + b * 64 + i];
    if (t < 64) {
        int j = t;
        float dx = x[(b * NN + j) * 3 + 0] - x[(b * NN + i) * 3 + 0];
        float dy = x[(b * NN + j) * 3 + 1] - x[(b * NN + i) * 3 + 1];
        float dz = x[(b * NN + j) * 3 + 2] - x[(b * NN + i) * 3 + 2];
        float d2 = dx * dx + dy * dy + dz * dz;
        float d  = sqrtf(fmaxf(d2, 0.f) + 1e-5f);
        float inv = 1.f / (d + 1e-5f);
        s_xhat[j * 4 + 0] = dx * inv;
        s_xhat[j * 4 + 1] = dy * inv;
        s_xhat[j * 4 + 2] = dz * inv;
        s_xhat[j * 4 + 3] = d;
    }
    __syncthreads();

    // ---------- P1: rbf A slots 0..7, one slot per thread ----------
    {
        int j = t & 63, sl = t >> 6;    // sl 0..7
        float d = s_xhat[j * 4 + 3];
        float cut = 0.5f * (__cosf(d * 0.6283185307179586f) + 1.f) * (d < 5.f ? 1.f : 0.f);
        float emd = __expf(-d);
        const float* mcol = mid_T + b * 64 + j;
        short8 val;
#pragma unroll
        for (int e = 0; e < 8; e++) {
            int r = sl * 8 + e;
            float o;
            if (r < 50) {
                float m = mcol[r * 1024] + s_midi[r];
                float df = emd - rbf_means[r];
                o = cut * __expf(-rbf_betas[r] * df * df) * m;
            } else if (r == 50) o = d;
            else o = 0.f;
            val[e] = f2bfs(o);
        }
        A8w[sl * 64 + j] = val;
    }
    __syncthreads();

    // ---------- P2 (MFMA K=64, C-init E1j+E1i): u -> slots 8..15 ----------
    {
        int f = wn * 16 + lr;
        const float* e1b = e1 + (size_t)b * 64 * 128;
        float e1i_v = e1b[i * 128 + 64 + f];
        f32x4 acc[2];
#pragma unroll
        for (int jj = 0; jj < 2; jj++) {
            int jt = wj * 2 + jj;
#pragma unroll
            for (int r = 0; r < 4; r++) {
                int j = jt * 16 + lg * 4 + r;
                acc[jj][r] = e1b[j * 128 + f] + e1i_v;
            }
        }
#pragma unroll
        for (int ks = 0; ks < 2; ks++) {
            short8 bb = We1p[(wn * 2 + ks) * 64 + l];
#pragma unroll
            for (int jj = 0; jj < 2; jj++) {
                short8 aa = A8[(ks * 4 + lg) * 64 + (wj * 2 + jj) * 16 + lr];
                acc[jj] = __builtin_amdgcn_mfma_f32_16x16x32_bf16(aa, bb, acc[jj], 0, 0, 0);
            }
        }
#pragma unroll
        for (int jj = 0; jj < 2; jj++)
#pragma unroll
            for (int r = 0; r < 4; r++) {
                int j = (wj * 2 + jj) * 16 + lg * 4 + r;
                s_A[(((f >> 3) + 8) * 64 + j) * 8 + (f & 7)] = f2bfs(siluf(acc[jj][r]));
            }
        __syncthreads();
    }

    // ---------- P3 (MFMA): h_e = u @ W_e2 + b_e2 -> s_he; waves 0/1 also sem = u @ We2s ----------
    {
        f32x4 acc[2], acc2[2];
#pragma unroll
        for (int jj = 0; jj < 2; jj++) {
            acc[jj][0] = 0.f; acc[jj][1] = 0.f; acc[jj][2] = 0.f; acc[jj][3] = 0.f;
            acc2[jj][0] = 0.f; acc2[jj][1] = 0.f; acc2[jj][2] = 0.f; acc2[jj][3] = 0.f;
        }
#pragma unroll
        for (int ks = 0; ks < 2; ks++) {
            short8 bb = We2p[(wn * 2 + ks) * 64 + l];
            short8 bb2 = We2p[(8 + ks) * 64 + l];
#pragma unroll
            for (int jj = 0; jj < 2; jj++) {
                short8 aa = A8[(8 + ks * 4 + lg) * 64 + (wj * 2 + jj) * 16 + lr];
                acc[jj] = __builtin_amdgcn_mfma_f32_16x16x32_bf16(aa, bb, acc[jj], 0, 0, 0);
                if (wn == 0)
                    acc2[jj] = __builtin_amdgcn_mfma_f32_16x16x32_bf16(aa, bb2, acc2[jj], 0, 0, 0);
            }
        }
        int f = wn * 16 + lr;
        float be2 = b_e2[f];
#pragma unroll
        for (int jj = 0; jj < 2; jj++)
#pragma unroll
            for (int r = 0; r < 4; r++) {
                int j = (wj * 2 + jj) * 16 + lg * 4 + r;
                s_he[j * 72 + f] = f2bfs(acc[jj][r] + be2);
            }
        if (wn == 0 && lr < 4) {
#pragma unroll
            for (int jj = 0; jj < 2; jj++)
#pragma unroll
                for (int r = 0; r < 4; r++) {
                    int j = (wj * 2 + jj) * 16 + lg * 4 + r;
                    s_sem[j * 4 + lr] = acc2[jj][r];
                }
        }
        __syncthreads();
    }

    // ---------- P4: sem/euc softmax over j (waves 0..3 only) ----------
    if (t < 256) {
        int hh = w, j = l;
        float acc = s_sem[j * 4 + hh] + bs2[hh];
        float cel = fmaxf(acc, 0.f) + fminf(0.f, 2.f * (__expf(0.5f * acc) - 1.f));
        float diag = (j == i) ? 1e5f : 0.f;
        float slog = cel - diag;
        float m1 = wave_max(slog);
        float e1v = __expf(slog - m1);
        float sem = e1v / wave_sum(e1v);
        float gam = __expf(log_gamma[hh]);
        float elog = -(s_xhat[j * 4 + 3] + diag) * gam;
        float m2 = wave_max(elog);
        float e2 = __expf(elog - m2);
        float euc = e2 / wave_sum(e2);
        float a = sem * euc;
        a = a / wave_sum(a);
        s_att[j * 4 + hh] = a;
    }
    __syncthreads();

    // ---------- P5: hagg -> global (512 threads; 4-way j split) ----------
    {
        int f2 = t >> 4, hh = (t >> 2) & 3, jq = t & 3;   // f2 0..31
        float a0 = 0.f, a1 = 0.f;
#pragma unroll 8
        for (int jjj = 0; jjj < 16; jjj++) {
            int j = jq * 16 + jjj;
            float at = s_att[j * 4 + hh];
            unsigned u = *(const unsigned*)(s_he + j * 72 + 2 * f2);
            a0 += bflo(u) * at;
            a1 += bfhi(u) * at;
        }
        a0 += __shfl_xor(a0, 1); a0 += __shfl_xor(a0, 2);
        a1 += __shfl_xor(a1, 1); a1 += __shfl_xor(a1, 2);
        if (jq == 0) {
            hagg_g[bi * 256 + (2 * f2) * 4 + hh]     = a0;
            hagg_g[bi * 256 + (2 * f2 + 1) * 4 + hh] = a1;
        }
    }

    // ---------- P6: xmix GEMM, two K-halves ----------
    f32x4 acc[2][4];
#pragma unroll
    for (int jj = 0; jj < 2; jj++)
#pragma unroll
        for (int nt = 0; nt < 4; nt++) { acc[jj][nt][0] = 0.f; acc[jj][nt][1] = 0.f; acc[jj][nt][2] = 0.f; acc[jj][nt][3] = 0.f; }

    for (int half = 0; half < 2; half++) {
        {   // build hea slots 0..15: 2 slots per thread
            int j = t & 63, kc = t >> 6;     // kc 0..7
            float a0 = s_att[j * 4 + 0], a1 = s_att[j * 4 + 1];
            float a2 = s_att[j * 4 + 2], a3 = s_att[j * 4 + 3];
            float av[4] = { a0, a1, a2, a3 };
            uint2 hv = *(const uint2*)(s_he + j * 72 + (half * 32 + kc * 4));
            float hf[4] = { bflo(hv.x), bfhi(hv.x), bflo(hv.y), bfhi(hv.y) };
#pragma unroll
            for (int s = 0; s < 2; s++) {
                int sl = kc * 2 + s;
                short8 val;
#pragma unroll
                for (int e = 0; e < 8; e++)
                    val[e] = f2bfs(hf[s * 2 + (e >> 2)] * av[e & 3]);
                A8w[sl * 64 + j] = val;
            }
        }
        __syncthreads();
#pragma unroll
        for (int ks = 0; ks < 4; ks++) {
            short8 aa[2];
#pragma unroll
            for (int jj = 0; jj < 2; jj++) aa[jj] = A8[(ks * 4 + lg) * 64 + (wj * 2 + jj) * 16 + lr];
#pragma unroll
            for (int nt = 0; nt < 4; nt++) {
                short8 bb = Wxp[((wn * 4 + nt) * 8 + half * 4 + ks) * 64 + l];
#pragma unroll
                for (int jj = 0; jj < 2; jj++)
                    acc[jj][nt] = __builtin_amdgcn_mfma_f32_16x16x32_bf16(aa[jj], bb, acc[jj][nt], 0, 0, 0);
            }
        }
        __syncthreads();
    }

    // epilogue: tanh, xhat-weight, reduce over this wave's 32 j -> LDS partials -> combine
    {
        float* sp = (float*)s_A;   // 2 x 768 floats, safe: all A-reads done at last barrier
#pragma unroll
        for (int nt = 0; nt < 4; nt++) {
            float p0 = 0.f, p1 = 0.f, p2 = 0.f;
#pragma unroll
            for (int jj = 0; jj < 2; jj++)
#pragma unroll
                for (int r = 0; r < 4; r++) {
                    int j = (wj * 2 + jj) * 16 + lg * 4 + r;
                    float th = tanhfast(acc[jj][nt][r]);
                    p0 += s_xhat[j * 4 + 0] * th;
                    p1 += s_xhat[j * 4 + 1] * th;
                    p2 += s_xhat[j * 4 + 2] * th;
                }
            p0 += __shfl_xor(p0, 16); p0 += __shfl_xor(p0, 32);
            p1 += __shfl_xor(p1, 16); p1 += __shfl_xor(p1, 32);
            p2 += __shfl_xor(p2, 16); p2 += __shfl_xor(p2, 32);
            if (lg == 0) {
                int c = wn * 64 + nt * 16 + lr;
                sp[wj * 768 + c * 3 + 0] = p0;
                sp[wj * 768 + c * 3 + 1] = p1;
                sp[wj * 768 + c * 3 + 2] = p2;
            }
        }
        __syncthreads();
        if (t < 256) {
            int c = t;
            float* cg = comb_g + bi * 768 + c * 3;
            cg[0] = (sp[c * 3 + 0] + sp[768 + c * 3 + 0]) * (1.f / 64.f);
            cg[1] = (sp[c * 3 + 1] + sp[768 + c * 3 + 1]) * (1.f / 64.f);
            cg[2] = (sp[c * 3 + 2] + sp[768 + c * 3 + 2]) * (1.f / 64.f);
        }
    }
}

// =============== tail: 64 blocks x 16-node tiles, MFMA MLP chain (round-4 proven) ===============
__global__ __launch_bounds__(256)
void sake_tail_kernel(
    const float* __restrict__ h, const float* __restrict__ x, const float* __restrict__ v,
    const float* __restrict__ hagg_g, const float* __restrict__ comb_g,
    const float* __restrict__ b_post1, const float* __restrict__ b_post2,
    const float* __restrict__ b_node1, const float* __restrict__ b_node2,
    const float* __restrict__ b_vel1,
    const float* __restrict__ W_vel2, const float* __restrict__ W_vmix,
    const short* __restrict__ wpack,
    float* __restrict__ out_h, float* __restrict__ out_x, float* __restrict__ out_v)
{
    const int g0 = blockIdx.x * 16;
    const int t = threadIdx.x;
    const int w = t >> 6, l = t & 63, lr = l & 15, lg = l >> 4;

    __shared__ __align__(16) short s_Aa[88 * 16 * 8];
    __shared__ float s_wv[256];
    __shared__ float s_wv2[64];
    __shared__ float s_red[4][16];

    const short8* A8  = (const short8*)s_Aa;
    const short8* PO1p = (const short8*)(wpack + WS_PO1);
    const short8* NO1p = (const short8*)(wpack + WS_NO1);
    const short8* PO2p = (const short8*)(wpack + WS_PO2);
    const short8* NO2p = (const short8*)(wpack + WS_NO2);
    const short8* VE1p = (const short8*)(wpack + WS_VE1);

    {
        s_wv[t] = W_vmix[t];
        if (t < 64) s_wv2[t] = W_vel2[t];
        int n = t & 15, c0 = (t >> 4) * 16;
        const float* cg = comb_g + (g0 + n) * 768;
        const float* ha = hagg_g + (g0 + n) * 256;
#pragma unroll
        for (int cc = 0; cc < 16; cc++) {
            int c = c0 + cc;
            float v0 = cg[c * 3 + 0], v1 = cg[c * 3 + 1], v2 = cg[c * 3 + 2];
            float hcp = v0 * v0 + v1 * v1 + v2 * v2;
            s_Aa[((c >> 3) * 16 + n) * 8 + (c & 7)] = f2bfs(hcp);
            s_Aa[((40 + (c >> 3)) * 16 + n) * 8 + (c & 7)] = f2bfs(ha[c]);
        }
        int f0 = (t >> 4) * 4;
#pragma unroll
        for (int ff = 0; ff < 4; ff++) {
            int f = f0 + ff;
            s_Aa[((32 + (f >> 3)) * 16 + n) * 8 + (f & 7)] = f2bfs(h[(g0 + n) * 64 + f]);
        }
    }
    __syncthreads();

    {   // post1 (K=256) -> slots 80..87
        f32x4 acc = {0.f, 0.f, 0.f, 0.f};
#pragma unroll
        for (int ks = 0; ks < 8; ks++) {
            short8 aa = A8[(ks * 4 + lg) * 16 + lr];
            short8 bb = PO1p[((w * 8 + ks) * 4 + lg) * 16 + lr];
            acc = __builtin_amdgcn_mfma_f32_16x16x32_bf16(aa, bb, acc, 0, 0, 0);
        }
        int f = w * 16 + lr;
        float bp = b_post1[f];
        __syncthreads();
#pragma unroll
        for (int r = 0; r < 4; r++) {
            int n = lg * 4 + r;
            s_Aa[((80 + (f >> 3)) * 16 + n) * 8 + (f & 7)] = f2bfs(siluf(acc[r] + bp));
        }
        __syncthreads();
    }
    {   // post2 -> hcomb slots 72..79
        f32x4 acc = {0.f, 0.f, 0.f, 0.f};
#pragma unroll
        for (int ks = 0; ks < 2; ks++) {
            short8 aa = A8[((80 + ks * 4 + lg)) * 16 + lr];
            short8 bb = PO2p[((w * 2 + ks) * 4 + lg) * 16 + lr];
            acc = __builtin_amdgcn_mfma_f32_16x16x32_bf16(aa, bb, acc, 0, 0, 0);
        }
        int f = w * 16 + lr;
        float bp = b_post2[f];
#pragma unroll
        for (int r = 0; r < 4; r++) {
            int n = lg * 4 + r;
            s_Aa[((72 + (f >> 3)) * 16 + n) * 8 + (f & 7)] = f2bfs(siluf(acc[r] + bp));
        }
        __syncthreads();
    }
    {   // node1 (K=384) -> slots 0..7
        f32x4 acc = {0.f, 0.f, 0.f, 0.f};
#pragma unroll
        for (int ks = 0; ks < 12; ks++) {
            short8 aa = A8[((32 + ks * 4 + lg)) * 16 + lr];
            short8 bb = NO1p[((w * 12 + ks) * 4 + lg) * 16 + lr];
            acc = __builtin_amdgcn_mfma_f32_16x16x32_bf16(aa, bb, acc, 0, 0, 0);
        }
        int f = w * 16 + lr;
        float bp = b_node1[f];
#pragma unroll
        for (int r = 0; r < 4; r++) {
            int n = lg * 4 + r;
            s_Aa[((f >> 3) * 16 + n) * 8 + (f & 7)] = f2bfs(siluf(acc[r] + bp));
        }
        __syncthreads();
    }
    {   // node2 + residual -> out_h, vel1-A slots 8..15
        f32x4 acc = {0.f, 0.f, 0.f, 0.f};
#pragma unroll
        for (int ks = 0; ks < 2; ks++) {
            short8 aa = A8[(ks * 4 + lg) * 16 + lr];
            short8 bb = NO2p[((w * 2 + ks) * 4 + lg) * 16 + lr];
            acc = __builtin_amdgcn_mfma_f32_16x16x32_bf16(aa, bb, acc, 0, 0, 0);
        }
        int f = w * 16 + lr;
        float bp = b_node2[f];
#pragma unroll
        for (int r = 0; r < 4; r++) {
            int n = lg * 4 + r;
            float ho = h[(g0 + n) * 64 + f] + siluf(acc[r] + bp);
            out_h[(g0 + n) * 64 + f] = ho;
            s_Aa[((8 + (f >> 3)) * 16 + n) * 8 + (f & 7)] = f2bfs(ho);
        }
        __syncthreads();
    }
    {   // vel1 -> gate partials
        f32x4 acc = {0.f, 0.f, 0.f, 0.f};
#pragma unroll
        for (int ks = 0; ks < 2; ks++) {
            short8 aa = A8[((8 + ks * 4 + lg)) * 16 + lr];
            short8 bb = VE1p[((w * 2 + ks) * 4 + lg) * 16 + lr];
            acc = __builtin_amdgcn_mfma_f32_16x16x32_bf16(aa, bb, acc, 0, 0, 0);
        }
        int f = w * 16 + lr;
        float bp = b_vel1[f];
        float wv2 = s_wv2[f];
#pragma unroll
        for (int r = 0; r < 4; r++) {
            float pv = siluf(acc[r] + bp) * wv2;
            pv += __shfl_xor(pv, 1); pv += __shfl_xor(pv, 2);
            pv += __shfl_xor(pv, 4); pv += __shfl_xor(pv, 8);
            if (lr == 0) s_red[w][lg * 4 + r] = pv;
        }
        __syncthreads();
    }
    {   // gate + delta_v + outputs
        int n = t >> 4, qq = t & 15;
        float p0 = 0.f, p1 = 0.f, p2 = 0.f;
        const float* cg = comb_g + (g0 + n) * 768;
#pragma unroll
        for (int cc = 0; cc < 16; cc++) {
            int c = qq * 16 + cc;
            float wv = s_wv[c];
            p0 += cg[c * 3 + 0] * wv;
            p1 += cg[c * 3 + 1] * wv;
            p2 += cg[c * 3 + 2] * wv;
        }
        p0 += __shfl_xor(p0, 1); p0 += __shfl_xor(p0, 2); p0 += __shfl_xor(p0, 4); p0 += __shfl_xor(p0, 8);
        p1 += __shfl_xor(p1, 1); p1 += __shfl_xor(p1, 2); p1 += __shfl_xor(p1, 4); p1 += __shfl_xor(p1, 8);
        p2 += __shfl_xor(p2, 1); p2 += __shfl_xor(p2, 2); p2 += __shfl_xor(p2, 4); p2 += __shfl_xor(p2, 8);
        if (qq == 0) {
            float g = s_red[0][n] + s_red[1][n] + s_red[2][n] + s_red[3][n];
            g = 2.f / (1.f + __expf(-g));
            float dv0 = p0 + g * v[(g0 + n) * 3 + 0];
            float dv1 = p1 + g * v[(g0 + n) * 3 + 1];
            float dv2 = p2 + g * v[(g0 + n) * 3 + 2];
            out_v[(g0 + n) * 3 + 0] = dv0;
            out_v[(g0 + n) * 3 + 1] = dv1;
            out_v[(g0 + n) * 3 + 2] = dv2;
            out_x[(g0 + n) * 3 + 0] = x[(g0 + n) * 3 + 0] + dv0;
            out_x[(g0 + n) * 3 + 1] = x[(g0 + n) * 3 + 1] + dv1;
            out_x[(g0 + n) * 3 + 2] = x[(g0 + n) * 3 + 2] + dv2;
        }
    }
}

extern "C" void kernel_launch(void* const* d_in, const int* in_sizes, int n_in,
                              void* d_out, int out_size, void* d_ws, size_t ws_size,
                              hipStream_t stream) {
    const float* h        = (const float*)d_in[0];
    const float* x        = (const float*)d_in[1];
    const float* v        = (const float*)d_in[2];
    const float* W_in     = (const float*)d_in[3];
    const float* b_in     = (const float*)d_in[4];
    const float* rbf_m    = (const float*)d_in[5];
    const float* rbf_b    = (const float*)d_in[6];
    const float* W_e1     = (const float*)d_in[7];
    const float* b_e1     = (const float*)d_in[8];
    const float* W_e2     = (const float*)d_in[9];
    const float* b_e2     = (const float*)d_in[10];
    const float* W_sem    = (const float*)d_in[11];
    const float* b_sem    = (const float*)d_in[12];
    const float* log_g    = (const float*)d_in[13];
    const float* W_xmix   = (const float*)d_in[14];
    const float* W_post1  = (const float*)d_in[15];
    const float* b_post1  = (const float*)d_in[16];
    const float* W_post2  = (const float*)d_in[17];
    const float* b_post2  = (const float*)d_in[18];
    const float* W_node1  = (const float*)d_in[19];
    const float* b_node1  = (const float*)d_in[20];
    const float* W_node2  = (const float*)d_in[21];
    const float* b_node2  = (const float*)d_in[22];
    const float* W_vel1   = (const float*)d_in[23];
    const float* b_vel1   = (const float*)d_in[24];
    const float* W_vel2   = (const float*)d_in[25];
    const float* W_vmix   = (const float*)d_in[26];

    float* out   = (float*)d_out;
    float* out_h = out;
    float* out_x = out + NB * NN * NF;
    float* out_v = out + NB * NN * NF + NB * NN * 3;

    short* wpack = (short*)d_ws;
    float* wsf   = (float*)d_ws;
    float* mid_T = wsf + MID_F;
    float* e1    = wsf + E1_F;
    float* hagg  = wsf + HAGG_F;
    float* comb  = wsf + COMB_F;
    float* bs2   = wsf + BS2_F;

    prep_kernel<<<64 + 1024, 256, 0, stream>>>(
        W_e1, b_e1, W_e2, b_e2, W_sem, b_sem, W_xmix,
        W_post1, W_node1, W_post2, W_node2, W_vel1,
        h, W_in, b_in, wpack, mid_T, e1, bs2);

    sake_edge_kernel<<<NB * NN, 512, 0, stream>>>(
        x, mid_T, e1, rbf_m, rbf_b, b_e2, bs2, log_g,
        wpack, hagg, comb);

    sake_tail_kernel<<<64, 256, 0, stream>>>(
        h, x, v, hagg, comb,
        b_post1, b_post2, b_node1, b_node2, b_vel1,
        W_vel2, W_vmix, wpack, out_h, out_x, out_v);
}

// Round 8
// 59.075 us; speedup vs baseline: 1.9864x; 1.0472x over previous
//
#include <hip/hip_runtime.h>
#include <math.h>

#define NB 16
#define NN 64
#define NF 64
#define NH 4
#define NR 50
#define NC 256

typedef __attribute__((ext_vector_type(8))) short short8;
typedef __attribute__((ext_vector_type(4))) float f32x4;

// ---- wpack short offsets ----
#define WS_WE1R 0          // 512 entries (K=64 rbf part of W_e1)
#define WS_WE2  4096       // 640 entries (512 We2 + 128 We2s)
#define WS_WX   9216       // 8192 entries [wn(16)][ks8(8)][lane]
#define WS_PO1  74752      // 2048
#define WS_NO1  91136      // 3072
#define WS_PO2  115712     // 512
#define WS_NO2  119808     // 512
#define WS_VE1  123904     // 512 -> shorts end 128000
// ---- float offsets ----
#define MID_F   64000
#define E1_F    (MID_F + 131072)
#define HAGG_F  (E1_F + 131072)
#define COMB_F  (HAGG_F + 262144)
#define BS2_F   (COMB_F + 786432)

__device__ __forceinline__ float siluf(float x) { return x / (1.f + __expf(-x)); }
__device__ __forceinline__ float tanhfast(float x) { return 1.f - 2.f / (__expf(2.f * x) + 1.f); }

__device__ __forceinline__ short f2bfs(float f) {
    __bf16 b = (__bf16)f;
    union { __bf16 b; short s; } u; u.b = b; return u.s;
}
__device__ __forceinline__ float bf1(ushort u) {
    union { unsigned u; float f; } c; c.u = ((unsigned)u) << 16; return c.f;
}
__device__ __forceinline__ float bflo(unsigned u) {
    union { unsigned u; float f; } c; c.u = u << 16; return c.f;
}
__device__ __forceinline__ float bfhi(unsigned u) {
    union { unsigned u; float f; } c; c.u = u & 0xFFFF0000u; return c.f;
}

// =============== prep: weight packs + bs2 + per-node precomputes ===============
__global__ __launch_bounds__(256)
void prep_kernel(const float* __restrict__ W_e1, const float* __restrict__ b_e1,
                 const float* __restrict__ W_e2, const float* __restrict__ b_e2,
                 const float* __restrict__ W_sem, const float* __restrict__ b_sem,
                 const float* __restrict__ W_xmix,
                 const float* __restrict__ W_post1, const float* __restrict__ W_node1,
                 const float* __restrict__ W_post2, const float* __restrict__ W_node2,
                 const float* __restrict__ W_vel1,
                 const float* __restrict__ h, const float* __restrict__ W_in,
                 const float* __restrict__ b_in,
                 short* __restrict__ wpack, float* __restrict__ mid,
                 float* __restrict__ e1, float* __restrict__ bs2)
{
    int blk = blockIdx.x, t = threadIdx.x;
    if (blk < 63) {
        int s = blk * 256 + t;
        if (s >= 16000) return;
        short8 val;
        if (s < 512) {               // W_e1 rbf part K=64
            int cl = s & 15, g = (s >> 4) & 3, q = s >> 6;
            int ks = q & 1, nt = q >> 1;
            int c = nt * 16 + cl, k0 = 32 * ks + 8 * g;
#pragma unroll
            for (int i = 0; i < 8; i++) {
                int kr = k0 + i;
                float f = (kr < 50) ? W_e1[(128 + kr) * NF + c] : (kr == 50 ? W_e1[178 * NF + c] : 0.f);
                val[i] = f2bfs(f);
            }
            *(short8*)(&wpack[WS_WE1R + s * 8]) = val;
        } else if (s < 1152) {        // W_e2 (nt 0..3) + We2s = We2@Wsem (nt 4)
            int u = s - 512;
            int cl = u & 15, g = (u >> 4) & 3, q = u >> 6;
            int ks = q & 1, nt = q >> 1;
            int c = nt * 16 + cl, k0 = 32 * ks + 8 * g;
#pragma unroll
            for (int i = 0; i < 8; i++) {
                int k = k0 + i;
                float f;
                if (c < 64) f = W_e2[k * NF + c];
                else {
                    int cc = c - 64;
                    if (cc < 4) {
                        f = 0.f;
                        for (int m = 0; m < 64; m++) f += W_e2[k * NF + m] * W_sem[m * NH + cc];
                    } else f = 0.f;
                }
                val[i] = f2bfs(f);
            }
            *(short8*)(&wpack[WS_WE2 + u * 8]) = val;
        } else if (s < 9344) {        // W_xmix K=256 N=256
            int u = s - 1152;
            int cl = u & 15, g = (u >> 4) & 3, q = u >> 6;
            int ks = q & 7, wn = q >> 3;
            int c = (wn >> 2) * 64 + (wn & 3) * 16 + cl, k0 = 32 * ks + 8 * g;
#pragma unroll
            for (int i = 0; i < 8; i++) val[i] = f2bfs(W_xmix[(k0 + i) * NC + c]);
            *(short8*)(&wpack[WS_WX + u * 8]) = val;
        } else if (s < 11392) {       // W_post1 K=256 N=64
            int u = s - 9344;
            int cl = u & 15, g = (u >> 4) & 3, q = u >> 6;
            int ks = q & 7, nt = q >> 3;
            int c = nt * 16 + cl, k0 = 32 * ks + 8 * g;
#pragma unroll
            for (int i = 0; i < 8; i++) val[i] = f2bfs(W_post1[(k0 + i) * NF + c]);
            *(short8*)(&wpack[WS_PO1 + u * 8]) = val;
        } else if (s < 14464) {       // W_node1 K=384
            int u = s - 11392;
            int cl = u & 15, g = (u >> 4) & 3, q = u >> 6;
            int ks = q % 12, nt = q / 12;
            int c = nt * 16 + cl, k0 = 32 * ks + 8 * g;
#pragma unroll
            for (int i = 0; i < 8; i++) val[i] = f2bfs(W_node1[(k0 + i) * NF + c]);
            *(short8*)(&wpack[WS_NO1 + u * 8]) = val;
        } else if (s < 14976) {       // W_post2
            int u = s - 14464;
            int cl = u & 15, g = (u >> 4) & 3, q = u >> 6;
            int ks = q & 1, nt = q >> 1;
            int c = nt * 16 + cl, k0 = 32 * ks + 8 * g;
#pragma unroll
            for (int i = 0; i < 8; i++) val[i] = f2bfs(W_post2[(k0 + i) * NF + c]);
            *(short8*)(&wpack[WS_PO2 + u * 8]) = val;
        } else if (s < 15488) {       // W_node2
            int u = s - 14976;
            int cl = u & 15, g = (u >> 4) & 3, q = u >> 6;
            int ks = q & 1, nt = q >> 1;
            int c = nt * 16 + cl, k0 = 32 * ks + 8 * g;
#pragma unroll
            for (int i = 0; i < 8; i++) val[i] = f2bfs(W_node2[(k0 + i) * NF + c]);
            *(short8*)(&wpack[WS_NO2 + u * 8]) = val;
        } else {                      // W_vel1
            int u = s - 15488;
            int cl = u & 15, g = (u >> 4) & 3, q = u >> 6;
            int ks = q & 1, nt = q >> 1;
            int c = nt * 16 + cl, k0 = 32 * ks + 8 * g;
#pragma unroll
            for (int i = 0; i < 8; i++) val[i] = f2bfs(W_vel1[(k0 + i) * NF + c]);
            *(short8*)(&wpack[WS_VE1 + u * 8]) = val;
        }
    } else if (blk == 63) {
        if (t < 4) {
            float acc = b_sem[t];
            for (int m = 0; m < 64; m++) acc += b_e2[m] * W_sem[m * NH + t];
            bs2[t] = acc;
        }
    } else {
        int node = blk - 64;
        __shared__ float s_hn[64];
        if (t < 64) s_hn[t] = h[node * NF + t];
        __syncthreads();
        if (t < 64) {                    // E1j
            float acc = 0.f;
#pragma unroll 8
            for (int k = 0; k < 64; k++) acc += s_hn[k] * W_e1[k * NF + t];
            e1[node * 128 + t] = acc;
        } else if (t < 128) {            // E1i + b_e1
            int f = t - 64;
            float acc = b_e1[f];
#pragma unroll 8
            for (int k = 0; k < 64; k++) acc += s_hn[k] * W_e1[(64 + k) * NF + f];
            e1[node * 128 + 64 + f] = acc;
        } else if (t < 178) {            // midj (row-major)
            int r = t - 128;
            float acc = 0.f;
#pragma unroll 8
            for (int k = 0; k < 64; k++) acc += s_hn[k] * W_in[k * NR + r];
            mid[node * 128 + r] = acc;
        } else if (t >= 192 && t < 242) { // midi (+b_in)
            int r = t - 192;
            float acc = b_in[r];
#pragma unroll 8
            for (int k = 0; k < 64; k++) acc += s_hn[k] * W_in[(64 + k) * NR + r];
            mid[node * 128 + 64 + r] = acc;
        }
    }
}

// =============== edge: ONE WAVE per (b,i); zero barriers ===============
__global__ __launch_bounds__(64)
void sake_edge_kernel(
    const float* __restrict__ x,
    const float* __restrict__ mid, const float* __restrict__ e1,
    const float* __restrict__ rbf_means, const float* __restrict__ rbf_betas,
    const float* __restrict__ b_e2, const float* __restrict__ bs2,
    const float* __restrict__ log_gamma,
    const short* __restrict__ wpack,
    float* __restrict__ hagg_g, float* __restrict__ comb_g)
{
    const int bi = blockIdx.x;
    const int b  = bi >> 6;
    const int i  = bi & 63;
    const int l  = threadIdx.x;          // lane
    const int lr = l & 15, lg = l >> 4;

    __shared__ __align__(16) short s_Ar[8 * 64 * 8];   // 8 KiB rbf-A fragments
    __shared__ __align__(16) short s_Au[8 * 64 * 8];   // 8 KiB u-A fragments
    __shared__ __align__(16) short s_he[64 * 72];      // 9 KiB h_e rows (stride 72)
    __shared__ float s_xhat[256];
    __shared__ float s_att[256];

    const short8* A8r  = (const short8*)s_Ar;
    short8*       A8rw = (short8*)s_Ar;
    const short8* A8u  = (const short8*)s_Au;
    const short8* We1p = (const short8*)(wpack + WS_WE1R);
    const short8* We2p = (const short8*)(wpack + WS_WE2);
    const short8* Wxp  = (const short8*)(wpack + WS_WX);

    // ---------- P1: geometry + rbf-A (lane = j) ----------
    {
        int j = l;
        float dx = x[(b * NN + j) * 3 + 0] - x[(b * NN + i) * 3 + 0];
        float dy = x[(b * NN + j) * 3 + 1] - x[(b * NN + i) * 3 + 1];
        float dz = x[(b * NN + j) * 3 + 2] - x[(b * NN + i) * 3 + 2];
        float d2 = dx * dx + dy * dy + dz * dz;
        float d  = sqrtf(fmaxf(d2, 0.f) + 1e-5f);
        float inv = 1.f / (d + 1e-5f);
        float4 xh = { dx * inv, dy * inv, dz * inv, d };
        *(float4*)(s_xhat + j * 4) = xh;

        float cut = 0.5f * (__cosf(d * 0.6283185307179586f) + 1.f) * (d < 5.f ? 1.f : 0.f);
        float emd = __expf(-d);
        const float* mj = mid + (size_t)(b * 64 + j) * 128;
        const float* mi = mid + (size_t)(b * 64 + i) * 128 + 64;
#pragma unroll
        for (int g = 0; g < 8; g++) {
            short8 val;
#pragma unroll
            for (int e = 0; e < 8; e++) {
                int r = g * 8 + e;
                float o;
                if (r < 50) {
                    float m = mj[r] + mi[r];
                    float df = emd - rbf_means[r];
                    o = cut * __expf(-rbf_betas[r] * df * df) * m;
                } else if (r == 50) o = d;
                else o = 0.f;
                val[e] = f2bfs(o);
            }
            A8rw[g * 64 + j] = val;
        }
    }

    // ---------- P2 (MFMA K=64, C-init E1j+E1i): u -> s_Au ----------
    {
        const float* e1b = e1 + (size_t)b * 64 * 128;
        float e1iv[4];
#pragma unroll
        for (int nt = 0; nt < 4; nt++) e1iv[nt] = e1b[i * 128 + 64 + nt * 16 + lr];
        f32x4 accU[4][4];
#pragma unroll
        for (int jt = 0; jt < 4; jt++)
#pragma unroll
            for (int nt = 0; nt < 4; nt++) {
                int f = nt * 16 + lr;
#pragma unroll
                for (int r = 0; r < 4; r++) {
                    int j = jt * 16 + lg * 4 + r;
                    accU[jt][nt][r] = e1b[j * 128 + f] + e1iv[nt];
                }
            }
#pragma unroll
        for (int ks = 0; ks < 2; ks++) {
            short8 aa[4];
#pragma unroll
            for (int jt = 0; jt < 4; jt++) aa[jt] = A8r[(ks * 4 + lg) * 64 + jt * 16 + lr];
#pragma unroll
            for (int nt = 0; nt < 4; nt++) {
                short8 bb = We1p[(nt * 2 + ks) * 64 + l];
#pragma unroll
                for (int jt = 0; jt < 4; jt++)
                    accU[jt][nt] = __builtin_amdgcn_mfma_f32_16x16x32_bf16(aa[jt], bb, accU[jt][nt], 0, 0, 0);
            }
        }
#pragma unroll
        for (int jt = 0; jt < 4; jt++)
#pragma unroll
            for (int nt = 0; nt < 4; nt++) {
                int f = nt * 16 + lr;
#pragma unroll
                for (int r = 0; r < 4; r++) {
                    int j = jt * 16 + lg * 4 + r;
                    s_Au[((f >> 3) * 64 + j) * 8 + (f & 7)] = f2bfs(siluf(accU[jt][nt][r]));
                }
            }
    }

    // ---------- P3 (MFMA): h_e = u@We2 + b_e2 -> s_he; sem = u@We2s (C-layout regs) ----------
    f32x4 accS[4];
    {
        f32x4 accE[4][4];
#pragma unroll
        for (int jt = 0; jt < 4; jt++) {
            accS[jt][0] = 0.f; accS[jt][1] = 0.f; accS[jt][2] = 0.f; accS[jt][3] = 0.f;
#pragma unroll
            for (int nt = 0; nt < 4; nt++) {
                accE[jt][nt][0] = 0.f; accE[jt][nt][1] = 0.f; accE[jt][nt][2] = 0.f; accE[jt][nt][3] = 0.f;
            }
        }
#pragma unroll
        for (int ks = 0; ks < 2; ks++) {
            short8 aa[4];
#pragma unroll
            for (int jt = 0; jt < 4; jt++) aa[jt] = A8u[(ks * 4 + lg) * 64 + jt * 16 + lr];
            short8 bb2 = We2p[(8 + ks) * 64 + l];
#pragma unroll
            for (int jt = 0; jt < 4; jt++)
                accS[jt] = __builtin_amdgcn_mfma_f32_16x16x32_bf16(aa[jt], bb2, accS[jt], 0, 0, 0);
#pragma unroll
            for (int nt = 0; nt < 4; nt++) {
                short8 bb = We2p[(nt * 2 + ks) * 64 + l];
#pragma unroll
                for (int jt = 0; jt < 4; jt++)
                    accE[jt][nt] = __builtin_amdgcn_mfma_f32_16x16x32_bf16(aa[jt], bb, accE[jt][nt], 0, 0, 0);
            }
        }
        float be2v[4];
#pragma unroll
        for (int nt = 0; nt < 4; nt++) be2v[nt] = b_e2[nt * 16 + lr];
#pragma unroll
        for (int jt = 0; jt < 4; jt++)
#pragma unroll
            for (int nt = 0; nt < 4; nt++) {
                int f = nt * 16 + lr;
#pragma unroll
                for (int r = 0; r < 4; r++) {
                    int j = jt * 16 + lg * 4 + r;
                    s_he[j * 72 + f] = f2bfs(accE[jt][nt][r] + be2v[nt]);
                }
            }
    }

    // ---------- P4: in-register softmax; normalizations cancel: att = e1*e2 / sum ----------
    {
        float gam = __expf(log_gamma[lr & 3]);
        float bsv = bs2[lr & 3];
        float cel[4][4], dj[4][4];
        float m1 = -1e30f, m2 = -1e30f;
#pragma unroll
        for (int jt = 0; jt < 4; jt++)
#pragma unroll
            for (int r = 0; r < 4; r++) {
                int j = jt * 16 + lg * 4 + r;
                float s = accS[jt][r] + bsv;
                float c = fmaxf(s, 0.f) + fminf(0.f, 2.f * (__expf(0.5f * s) - 1.f));
                float d = s_xhat[j * 4 + 3];
                if (j == i) { c -= 1e5f; d += 1e5f; }
                cel[jt][r] = c; dj[jt][r] = d;
                m1 = fmaxf(m1, c);
                m2 = fmaxf(m2, -d * gam);
            }
        m1 = fmaxf(m1, __shfl_xor(m1, 16)); m1 = fmaxf(m1, __shfl_xor(m1, 32));
        m2 = fmaxf(m2, __shfl_xor(m2, 16)); m2 = fmaxf(m2, __shfl_xor(m2, 32));
        float at[4][4];
        float S1 = 0.f, S2 = 0.f;
#pragma unroll
        for (int jt = 0; jt < 4; jt++)
#pragma unroll
            for (int r = 0; r < 4; r++) {
                float ev1 = __expf(cel[jt][r] - m1);
                float ev2 = __expf(-dj[jt][r] * gam - m2);
                cel[jt][r] = ev1; dj[jt][r] = ev2;
                S1 += ev1; S2 += ev2;
            }
        S1 += __shfl_xor(S1, 16); S1 += __shfl_xor(S1, 32);
        S2 += __shfl_xor(S2, 16); S2 += __shfl_xor(S2, 32);
        float S3 = 0.f;
        float inv12 = 1.f / (S1 * S2);
#pragma unroll
        for (int jt = 0; jt < 4; jt++)
#pragma unroll
            for (int r = 0; r < 4; r++) {
                at[jt][r] = cel[jt][r] * dj[jt][r] * inv12;
                S3 += at[jt][r];
            }
        S3 += __shfl_xor(S3, 16); S3 += __shfl_xor(S3, 32);
        float inv3 = 1.f / S3;
        if (lr < 4) {
#pragma unroll
            for (int jt = 0; jt < 4; jt++)
#pragma unroll
                for (int r = 0; r < 4; r++) {
                    int j = jt * 16 + lg * 4 + r;
                    s_att[j * 4 + lr] = at[jt][r] * inv3;
                }
        }
    }

    // ---------- P5: hagg (lane = f) ----------
    {
        float hg0 = 0.f, hg1 = 0.f, hg2 = 0.f, hg3 = 0.f;
#pragma unroll 8
        for (int j = 0; j < 64; j++) {
            float hev = bf1((ushort)s_he[j * 72 + l]);
            float4 at = *(const float4*)(s_att + j * 4);
            hg0 += hev * at.x; hg1 += hev * at.y; hg2 += hev * at.z; hg3 += hev * at.w;
        }
        float4 o = { hg0, hg1, hg2, hg3 };
        *(float4*)(hagg_g + bi * 256 + l * 4) = o;
    }

    // ---------- P6: xmix GEMM — 32 A-frags in regs, N in 4 quarters ----------
    {
        short8 fr[4][8];
#pragma unroll
        for (int jt = 0; jt < 4; jt++) {
            int j = jt * 16 + lr;
            float4 a = *(const float4*)(s_att + j * 4);
#pragma unroll
            for (int ks = 0; ks < 8; ks++) {
                unsigned hv = *(const unsigned*)(s_he + j * 72 + ks * 8 + lg * 2);
                float h0 = bflo(hv), h1 = bfhi(hv);
                short8 v;
                v[0] = f2bfs(h0 * a.x); v[1] = f2bfs(h0 * a.y);
                v[2] = f2bfs(h0 * a.z); v[3] = f2bfs(h0 * a.w);
                v[4] = f2bfs(h1 * a.x); v[5] = f2bfs(h1 * a.y);
                v[6] = f2bfs(h1 * a.z); v[7] = f2bfs(h1 * a.w);
                fr[jt][ks] = v;
            }
        }
#pragma unroll 1
        for (int nq = 0; nq < 4; nq++) {
            f32x4 acc[4][4];
#pragma unroll
            for (int jt = 0; jt < 4; jt++)
#pragma unroll
                for (int nt = 0; nt < 4; nt++) {
                    acc[jt][nt][0] = 0.f; acc[jt][nt][1] = 0.f;
                    acc[jt][nt][2] = 0.f; acc[jt][nt][3] = 0.f;
                }
#pragma unroll
            for (int ks = 0; ks < 8; ks++) {
#pragma unroll
                for (int nt = 0; nt < 4; nt++) {
                    short8 bb = Wxp[((nq * 4 + nt) * 8 + ks) * 64 + l];
#pragma unroll
                    for (int jt = 0; jt < 4; jt++)
                        acc[jt][nt] = __builtin_amdgcn_mfma_f32_16x16x32_bf16(fr[jt][ks], bb, acc[jt][nt], 0, 0, 0);
                }
            }
            // epilogue: tanh, xhat-weight, j-reduce
            float p[4][3];
#pragma unroll
            for (int nt = 0; nt < 4; nt++) { p[nt][0] = 0.f; p[nt][1] = 0.f; p[nt][2] = 0.f; }
#pragma unroll
            for (int jt = 0; jt < 4; jt++) {
#pragma unroll
                for (int r = 0; r < 4; r++) {
                    int j = jt * 16 + lg * 4 + r;
                    float4 xh = *(const float4*)(s_xhat + j * 4);
#pragma unroll
                    for (int nt = 0; nt < 4; nt++) {
                        float th = tanhfast(acc[jt][nt][r]);
                        p[nt][0] += xh.x * th;
                        p[nt][1] += xh.y * th;
                        p[nt][2] += xh.z * th;
                    }
                }
            }
#pragma unroll
            for (int nt = 0; nt < 4; nt++) {
#pragma unroll
                for (int k = 0; k < 3; k++) {
                    float val = p[nt][k];
                    val += __shfl_xor(val, 16);
                    val += __shfl_xor(val, 32);
                    if (lg == 0)
                        comb_g[bi * 768 + (nq * 64 + nt * 16 + lr) * 3 + k] = val * (1.f / 64.f);
                }
            }
        }
    }
}

// =============== tail: 64 blocks x 16-node tiles, MFMA MLP chain ===============
__global__ __launch_bounds__(256)
void sake_tail_kernel(
    const float* __restrict__ h, const float* __restrict__ x, const float* __restrict__ v,
    const float* __restrict__ hagg_g, const float* __restrict__ comb_g,
    const float* __restrict__ b_post1, const float* __restrict__ b_post2,
    const float* __restrict__ b_node1, const float* __restrict__ b_node2,
    const float* __restrict__ b_vel1,
    const float* __restrict__ W_vel2, const float* __restrict__ W_vmix,
    const short* __restrict__ wpack,
    float* __restrict__ out_h, float* __restrict__ out_x, float* __restrict__ out_v)
{
    const int g0 = blockIdx.x * 16;
    const int t = threadIdx.x;
    const int w = t >> 6, l = t & 63, lr = l & 15, lg = l >> 4;

    __shared__ __align__(16) short s_Aa[88 * 16 * 8];
    __shared__ float s_wv[256];
    __shared__ float s_wv2[64];
    __shared__ float s_red[4][16];

    const short8* A8  = (const short8*)s_Aa;
    const short8* PO1p = (const short8*)(wpack + WS_PO1);
    const short8* NO1p = (const short8*)(wpack + WS_NO1);
    const short8* PO2p = (const short8*)(wpack + WS_PO2);
    const short8* NO2p = (const short8*)(wpack + WS_NO2);
    const short8* VE1p = (const short8*)(wpack + WS_VE1);

    {
        s_wv[t] = W_vmix[t];
        if (t < 64) s_wv2[t] = W_vel2[t];
        int n = t & 15, c0 = (t >> 4) * 16;
        const float* cg = comb_g + (g0 + n) * 768;
        const float* ha = hagg_g + (g0 + n) * 256;
#pragma unroll
        for (int cc = 0; cc < 16; cc++) {
            int c = c0 + cc;
            float v0 = cg[c * 3 + 0], v1 = cg[c * 3 + 1], v2 = cg[c * 3 + 2];
            float hcp = v0 * v0 + v1 * v1 + v2 * v2;
            s_Aa[((c >> 3) * 16 + n) * 8 + (c & 7)] = f2bfs(hcp);
            s_Aa[((40 + (c >> 3)) * 16 + n) * 8 + (c & 7)] = f2bfs(ha[c]);
        }
        int f0 = (t >> 4) * 4;
#pragma unroll
        for (int ff = 0; ff < 4; ff++) {
            int f = f0 + ff;
            s_Aa[((32 + (f >> 3)) * 16 + n) * 8 + (f & 7)] = f2bfs(h[(g0 + n) * 64 + f]);
        }
    }
    __syncthreads();

    {   // post1 (K=256) -> slots 80..87
        f32x4 acc = {0.f, 0.f, 0.f, 0.f};
#pragma unroll
        for (int ks = 0; ks < 8; ks++) {
            short8 aa = A8[(ks * 4 + lg) * 16 + lr];
            short8 bb = PO1p[((w * 8 + ks) * 4 + lg) * 16 + lr];
            acc = __builtin_amdgcn_mfma_f32_16x16x32_bf16(aa, bb, acc, 0, 0, 0);
        }
        int f = w * 16 + lr;
        float bp = b_post1[f];
        __syncthreads();
#pragma unroll
        for (int r = 0; r < 4; r++) {
            int n = lg * 4 + r;
            s_Aa[((80 + (f >> 3)) * 16 + n) * 8 + (f & 7)] = f2bfs(siluf(acc[r] + bp));
        }
        __syncthreads();
    }
    {   // post2 -> hcomb slots 72..79
        f32x4 acc = {0.f, 0.f, 0.f, 0.f};
#pragma unroll
        for (int ks = 0; ks < 2; ks++) {
            short8 aa = A8[((80 + ks * 4 + lg)) * 16 + lr];
            short8 bb = PO2p[((w * 2 + ks) * 4 + lg) * 16 + lr];
            acc = __builtin_amdgcn_mfma_f32_16x16x32_bf16(aa, bb, acc, 0, 0, 0);
        }
        int f = w * 16 + lr;
        float bp = b_post2[f];
#pragma unroll
        for (int r = 0; r < 4; r++) {
            int n = lg * 4 + r;
            s_Aa[((72 + (f >> 3)) * 16 + n) * 8 + (f & 7)] = f2bfs(siluf(acc[r] + bp));
        }
        __syncthreads();
    }
    {   // node1 (K=384) -> slots 0..7
        f32x4 acc = {0.f, 0.f, 0.f, 0.f};
#pragma unroll
        for (int ks = 0; ks < 12; ks++) {
            short8 aa = A8[((32 + ks * 4 + lg)) * 16 + lr];
            short8 bb = NO1p[((w * 12 + ks) * 4 + lg) * 16 + lr];
            acc = __builtin_amdgcn_mfma_f32_16x16x32_bf16(aa, bb, acc, 0, 0, 0);
        }
        int f = w * 16 + lr;
        float bp = b_node1[f];
#pragma unroll
        for (int r = 0; r < 4; r++) {
            int n = lg * 4 + r;
            s_Aa[((f >> 3) * 16 + n) * 8 + (f & 7)] = f2bfs(siluf(acc[r] + bp));
        }
        __syncthreads();
    }
    {   // node2 + residual -> out_h, vel1-A slots 8..15
        f32x4 acc = {0.f, 0.f, 0.f, 0.f};
#pragma unroll
        for (int ks = 0; ks < 2; ks++) {
            short8 aa = A8[(ks * 4 + lg) * 16 + lr];
            short8 bb = NO2p[((w * 2 + ks) * 4 + lg) * 16 + lr];
            acc = __builtin_amdgcn_mfma_f32_16x16x32_bf16(aa, bb, acc, 0, 0, 0);
        }
        int f = w * 16 + lr;
        float bp = b_node2[f];
#pragma unroll
        for (int r = 0; r < 4; r++) {
            int n = lg * 4 + r;
            float ho = h[(g0 + n) * 64 + f] + siluf(acc[r] + bp);
            out_h[(g0 + n) * 64 + f] = ho;
            s_Aa[((8 + (f >> 3)) * 16 + n) * 8 + (f & 7)] = f2bfs(ho);
        }
        __syncthreads();
    }
    {   // vel1 -> gate partials
        f32x4 acc = {0.f, 0.f, 0.f, 0.f};
#pragma unroll
        for (int ks = 0; ks < 2; ks++) {
            short8 aa = A8[((8 + ks * 4 + lg)) * 16 + lr];
            short8 bb = VE1p[((w * 2 + ks) * 4 + lg) * 16 + lr];
            acc = __builtin_amdgcn_mfma_f32_16x16x32_bf16(aa, bb, acc, 0, 0, 0);
        }
        int f = w * 16 + lr;
        float bp = b_vel1[f];
        float wv2 = s_wv2[f];
#pragma unroll
        for (int r = 0; r < 4; r++) {
            float pv = siluf(acc[r] + bp) * wv2;
            pv += __shfl_xor(pv, 1); pv += __shfl_xor(pv, 2);
            pv += __shfl_xor(pv, 4); pv += __shfl_xor(pv, 8);
            if (lr == 0) s_red[w][lg * 4 + r] = pv;
        }
        __syncthreads();
    }
    {   // gate + delta_v + outputs
        int n = t >> 4, qq = t & 15;
        float p0 = 0.f, p1 = 0.f, p2 = 0.f;
        const float* cg = comb_g + (g0 + n) * 768;
#pragma unroll
        for (int cc = 0; cc < 16; cc++) {
            int c = qq * 16 + cc;
            float wv = s_wv[c];
            p0 += cg[c * 3 + 0] * wv;
            p1 += cg[c * 3 + 1] * wv;
            p2 += cg[c * 3 + 2] * wv;
        }
        p0 += __shfl_xor(p0, 1); p0 += __shfl_xor(p0, 2); p0 += __shfl_xor(p0, 4); p0 += __shfl_xor(p0, 8);
        p1 += __shfl_xor(p1, 1); p1 += __shfl_xor(p1, 2); p1 += __shfl_xor(p1, 4); p1 += __shfl_xor(p1, 8);
        p2 += __shfl_xor(p2, 1); p2 += __shfl_xor(p2, 2); p2 += __shfl_xor(p2, 4); p2 += __shfl_xor(p2, 8);
        if (qq == 0) {
            float g = s_red[0][n] + s_red[1][n] + s_red[2][n] + s_red[3][n];
            g = 2.f / (1.f + __expf(-g));
            float dv0 = p0 + g * v[(g0 + n) * 3 + 0];
            float dv1 = p1 + g * v[(g0 + n) * 3 + 1];
            float dv2 = p2 + g * v[(g0 + n) * 3 + 2];
            out_v[(g0 + n) * 3 + 0] = dv0;
            out_v[(g0 + n) * 3 + 1] = dv1;
            out_v[(g0 + n) * 3 + 2] = dv2;
            out_x[(g0 + n) * 3 + 0] = x[(g0 + n) * 3 + 0] + dv0;
            out_x[(g0 + n) * 3 + 1] = x[(g0 + n) * 3 + 1] + dv1;
            out_x[(g0 + n) * 3 + 2] = x[(g0 + n) * 3 + 2] + dv2;
        }
    }
}

extern "C" void kernel_launch(void* const* d_in, const int* in_sizes, int n_in,
                              void* d_out, int out_size, void* d_ws, size_t ws_size,
                              hipStream_t stream) {
    const float* h        = (const float*)d_in[0];
    const float* x        = (const float*)d_in[1];
    const float* v        = (const float*)d_in[2];
    const float* W_in     = (const float*)d_in[3];
    const float* b_in     = (const float*)d_in[4];
    const float* rbf_m    = (const float*)d_in[5];
    const float* rbf_b    = (const float*)d_in[6];
    const float* W_e1     = (const float*)d_in[7];
    const float* b_e1     = (const float*)d_in[8];
    const float* W_e2     = (const float*)d_in[9];
    const float* b_e2     = (const float*)d_in[10];
    const float* W_sem    = (const float*)d_in[11];
    const float* b_sem    = (const float*)d_in[12];
    const float* log_g    = (const float*)d_in[13];
    const float* W_xmix   = (const float*)d_in[14];
    const float* W_post1  = (const float*)d_in[15];
    const float* b_post1  = (const float*)d_in[16];
    const float* W_post2  = (const float*)d_in[17];
    const float* b_post2  = (const float*)d_in[18];
    const float* W_node1  = (const float*)d_in[19];
    const float* b_node1  = (const float*)d_in[20];
    const float* W_node2  = (const float*)d_in[21];
    const float* b_node2  = (const float*)d_in[22];
    const float* W_vel1   = (const float*)d_in[23];
    const float* b_vel1   = (const float*)d_in[24];
    const float* W_vel2   = (const float*)d_in[25];
    const float* W_vmix   = (const float*)d_in[26];

    float* out   = (float*)d_out;
    float* out_h = out;
    float* out_x = out + NB * NN * NF;
    float* out_v = out + NB * NN * NF + NB * NN * 3;

    short* wpack = (short*)d_ws;
    float* wsf   = (float*)d_ws;
    float* mid   = wsf + MID_F;
    float* e1    = wsf + E1_F;
    float* hagg  = wsf + HAGG_F;
    float* comb  = wsf + COMB_F;
    float* bs2   = wsf + BS2_F;

    prep_kernel<<<64 + 1024, 256, 0, stream>>>(
        W_e1, b_e1, W_e2, b_e2, W_sem, b_sem, W_xmix,
        W_post1, W_node1, W_post2, W_node2, W_vel1,
        h, W_in, b_in, wpack, mid, e1, bs2);

    sake_edge_kernel<<<NB * NN, 64, 0, stream>>>(
        x, mid, e1, rbf_m, rbf_b, b_e2, bs2, log_g,
        wpack, hagg, comb);

    sake_tail_kernel<<<64, 256, 0, stream>>>(
        h, x, v, hagg, comb,
        b_post1, b_post2, b_node1, b_node2, b_vel1,
        W_vel2, W_vmix, wpack, out_h, out_x, out_v);
}